// Round 10
// baseline (186.117 us; speedup 1.0000x reference)
//
#include <hip/hip_runtime.h>

#define L_RES 2000
#define DF 54
#define WIN 7

typedef short bf16x8 __attribute__((ext_vector_type(8)));
typedef float f32x4 __attribute__((ext_vector_type(4)));
typedef unsigned short ushort8v __attribute__((ext_vector_type(8)));

__device__ __forceinline__ unsigned short f2bf(float f) {
    unsigned int u = __float_as_uint(f);
    unsigned int r = (u + 0x7FFFu + ((u >> 16) & 1u)) >> 16;
    return (unsigned short)r;
}
__device__ __forceinline__ float bf2f(unsigned short h) {
    return __uint_as_float(((unsigned int)h) << 16);
}
// async global->LDS, 16B per lane; LDS dest = wave-uniform base + lane*16
__device__ __forceinline__ void gload16(const unsigned short* g, unsigned short* l) {
    __builtin_amdgcn_global_load_lds(
        (const __attribute__((address_space(1))) void*)g,
        (__attribute__((address_space(3))) void*)l, 16, 0, 0);
}

// ---------------- bert stage a: split beft into A2 = [hi | lo | hi], K=3072, 2048 rows ----------------
__global__ __launch_bounds__(256) void split_beft(const float* __restrict__ beft,
                                                  unsigned short* __restrict__ A2) {
    int l = blockIdx.x;
    int t = threadIdx.x;
    unsigned short* row = A2 + (size_t)l * 3072;
    for (int k = t; k < 1024; k += 256) {
        unsigned short hi = 0, lo = 0;
        if (l < L_RES) {
            float x = beft[(size_t)l * 1024 + k];
            hi = f2bf(x);
            lo = f2bf(x - bf2f(hi));
        }
        row[k] = hi;
        row[1024 + k] = lo;
        row[2048 + k] = hi;
    }
}

// ---------------- bert stage b: B2T[64][3072]: segs {hi,hi,lo} of Wb^T ----------------
__global__ __launch_bounds__(256) void b2t_build(const float* __restrict__ Wb,
                                                 unsigned short* __restrict__ B2T) {
    int idx = blockIdx.x * 256 + threadIdx.x;   // 64*3072 = 196608
    int n = idx / 3072, col = idx % 3072;
    int seg = col >> 10, k = col & 1023;
    unsigned short r = 0;
    if (n < DF) {
        float v = Wb[(size_t)k * DF + n];
        unsigned short hi = f2bf(v);
        r = (seg < 2) ? hi : f2bf(v - bf2f(hi));
    }
    B2T[idx] = r;
}

// ---------------- bert stage c: MFMA GEMM M=2048 N=64, K-split z=4 -> fp32 partials ----------------
__global__ __launch_bounds__(256) void bert_mfma(const unsigned short* __restrict__ A2,
                                                 const unsigned short* __restrict__ B2T,
                                                 float* __restrict__ bpart) {
    __shared__ unsigned short ldsA[128 * 64];
    __shared__ unsigned short ldsB[64 * 64];
    int t = threadIdx.x, w = t >> 6, lane = t & 63;
    int m0 = blockIdx.x * 128;
    int z = blockIdx.y;                       // 4 K-slices of 768
    long koff = (long)z * 768;
    int wr = w >> 1, wc = w & 1;
    int arow = lane & 15, kgrp = lane >> 4;

    const unsigned short* aS[4]; const unsigned short* bS[2];
    int aD[4], bD[2];
    #pragma unroll
    for (int j = 0; j < 4; ++j) {
        int s = j * 256 + t, r = s >> 3, c = s & 7;
        aS[j] = A2 + koff + (size_t)(m0 + r) * 3072 + c * 8;
        aD[j] = r * 64 + ((c ^ (r & 7)) * 8);
    }
    #pragma unroll
    for (int j = 0; j < 2; ++j) {
        int s = j * 256 + t, r = s >> 3, c = s & 7;
        bS[j] = B2T + koff + (size_t)r * 3072 + c * 8;
        bD[j] = r * 64 + ((c ^ (r & 7)) * 8);
    }
    f32x4 acc[4][2];
    #pragma unroll
    for (int mi = 0; mi < 4; ++mi)
        #pragma unroll
        for (int ni = 0; ni < 2; ++ni) acc[mi][ni] = (f32x4)(0.f);

    ushort8v va[4], vb[2];
    #pragma unroll
    for (int j = 0; j < 4; ++j) va[j] = *(const ushort8v*)(aS[j]);
    #pragma unroll
    for (int j = 0; j < 2; ++j) vb[j] = *(const ushort8v*)(bS[j]);

    for (int ks = 0; ks < 12; ++ks) {
        __syncthreads();
        #pragma unroll
        for (int j = 0; j < 4; ++j) *(ushort8v*)&ldsA[aD[j]] = va[j];
        #pragma unroll
        for (int j = 0; j < 2; ++j) *(ushort8v*)&ldsB[bD[j]] = vb[j];
        __syncthreads();
        if (ks + 1 < 12) {
            #pragma unroll
            for (int j = 0; j < 4; ++j) va[j] = *(const ushort8v*)(aS[j] + (ks + 1) * 64);
            #pragma unroll
            for (int j = 0; j < 2; ++j) vb[j] = *(const ushort8v*)(bS[j] + (ks + 1) * 64);
        }
        #pragma unroll
        for (int kk = 0; kk < 2; ++kk) {
            int chunk = kk * 4 + kgrp;
            bf16x8 af[4], bfr[2];
            #pragma unroll
            for (int mi = 0; mi < 4; ++mi) {
                int rl = wr * 64 + mi * 16 + arow;
                af[mi] = *(const bf16x8*)&ldsA[rl * 64 + ((chunk ^ (rl & 7)) * 8)];
            }
            #pragma unroll
            for (int ni = 0; ni < 2; ++ni) {
                int rl = wc * 32 + ni * 16 + arow;
                bfr[ni] = *(const bf16x8*)&ldsB[rl * 64 + ((chunk ^ (rl & 7)) * 8)];
            }
            #pragma unroll
            for (int mi = 0; mi < 4; ++mi)
                #pragma unroll
                for (int ni = 0; ni < 2; ++ni)
                    acc[mi][ni] = __builtin_amdgcn_mfma_f32_16x16x32_bf16(af[mi], bfr[ni], acc[mi][ni], 0, 0, 0);
        }
    }
    #pragma unroll
    for (int ni = 0; ni < 2; ++ni) {
        int n = wc * 32 + ni * 16 + arow;
        #pragma unroll
        for (int mi = 0; mi < 4; ++mi)
            #pragma unroll
            for (int r = 0; r < 4; ++r) {
                int m = m0 + wr * 64 + mi * 16 + kgrp * 4 + r;
                bpart[((size_t)z * 2048 + m) * 64 + n] = acc[mi][ni][r];
            }
    }
}

// ---------------- bert stage d: reduce 4 partials + bias -> f (L,54) ----------------
__global__ __launch_bounds__(64) void bert_reduce(const float* __restrict__ bpart,
                                                  const float* __restrict__ bb,
                                                  float* __restrict__ f) {
    int l = blockIdx.x, n = threadIdx.x;
    if (n < DF) {
        float s = bb[n];
        #pragma unroll
        for (int z = 0; z < 4; ++z) s += bpart[((size_t)z * 2048 + l) * 64 + n];
        f[(size_t)l * DF + n] = s;
    }
}

// ---------------- window gather + attn x2 + concat, 4 residues (1 wave each) ----------------
__device__ __forceinline__ void attn_layer_w(const float (*in)[DF], float (*out)[DF],
                                             float (*s)[WIN][WIN],
                                             const float* __restrict__ g,
                                             const float* __restrict__ b,
                                             float* mm, float* vv, int lane) {
    for (int idx = lane; idx < 3 * WIN * WIN; idx += 64) {
        int h = idx / 49, r = idx % 49, q = r / WIN, k = r % WIN;
        float sum = 0.f;
        #pragma unroll
        for (int d = 0; d < 18; ++d) sum = fmaf(in[q][h * 18 + d], in[k][h * 18 + d], sum);
        s[h][q][k] = sum;
    }
    __syncthreads();
    for (int idx = lane; idx < 3 * WIN; idx += 64) {
        int h = idx / WIN, q = idx % WIN;
        float mx = s[h][q][0];
        #pragma unroll
        for (int k = 1; k < WIN; ++k) mx = fmaxf(mx, s[h][q][k]);
        float e[WIN], sum = 0.f;
        #pragma unroll
        for (int k = 0; k < WIN; ++k) { e[k] = expf(s[h][q][k] - mx); sum += e[k]; }
        float inv = 1.f / sum;
        #pragma unroll
        for (int k = 0; k < WIN; ++k) s[h][q][k] = e[k] * inv;
    }
    __syncthreads();
    for (int idx = lane; idx < WIN * DF; idx += 64) {
        int q = idx / DF, c = idx % DF, h = c / 18;
        float sum = 0.f;
        #pragma unroll
        for (int k = 0; k < WIN; ++k) sum = fmaf(s[h][q][k], in[k][c], sum);
        out[q][c] = sum;
    }
    __syncthreads();
    for (int q = lane; q < WIN; q += 64) {
        float m = 0.f;
        for (int c = 0; c < DF; ++c) m += out[q][c];
        m *= (1.f / DF);
        float v = 0.f;
        for (int c = 0; c < DF; ++c) { float d0 = out[q][c] - m; v = fmaf(d0, d0, v); }
        v *= (1.f / DF);
        mm[q] = m; vv[q] = rsqrtf(v + 1e-5f);
    }
    __syncthreads();
    for (int idx = lane; idx < WIN * DF; idx += 64) {
        int q = idx / DF, c = idx % DF;
        out[q][c] = (out[q][c] - mm[q]) * vv[q] * g[c] + b[c];
    }
    __syncthreads();
}

__global__ __launch_bounds__(256) void window_attn4(const float* __restrict__ f,
                                                    const float* __restrict__ g1,
                                                    const float* __restrict__ b1,
                                                    const float* __restrict__ g2,
                                                    const float* __restrict__ b2,
                                                    float* __restrict__ cat) {
    int wv = threadIdx.x >> 6, lane = threadIdx.x & 63;
    int l = blockIdx.x * 4 + wv;
    __shared__ float w[4][WIN][DF], o1[4][WIN][DF], o2[4][WIN][DF];
    __shared__ float s[4][3][WIN][WIN];
    __shared__ float mm[4][WIN], vvv[4][WIN];
    bool boundary = (l <= WIN) || (l + WIN >= L_RES);
    for (int idx = lane; idx < WIN * DF; idx += 64) {
        int j = idx / DF, d = idx % DF;
        w[wv][j][d] = boundary ? (j == 0 ? f[(size_t)l * DF + d] : 0.f)
                               : f[(size_t)(l - 4 + j) * DF + d];
    }
    __syncthreads();
    attn_layer_w(w[wv], o1[wv], s[wv], g1, b1, mm[wv], vvv[wv], lane);
    attn_layer_w(o1[wv], o2[wv], s[wv], g2, b2, mm[wv], vvv[wv], lane);
    for (int idx = lane; idx < WIN * DF; idx += 64) {
        int j = idx / DF, d = idx % DF;
        cat[(size_t)l * 756 + j * 108 + d] = w[wv][j][d];
        cat[(size_t)l * 756 + j * 108 + DF + d] = o2[wv][j][d];
    }
}

// ---------------- transpose + f32->bf16: dst[n][m], rows m>=M zero-padded ----------------
__global__ __launch_bounds__(256) void transpose_to_bf16(const float* __restrict__ src,
                                                         unsigned short* __restrict__ dst,
                                                         int M, int N, int Mpad) {
    __shared__ float tile[32][33];
    int m0 = blockIdx.x * 32, n0 = blockIdx.y * 32;
    int c = threadIdx.x % 32, r0 = threadIdx.x / 32;
    #pragma unroll
    for (int rr = 0; rr < 4; ++rr) {
        int r = r0 + rr * 8, m = m0 + r;
        tile[r][c] = (m < M) ? src[(size_t)m * N + n0 + c] : 0.f;
    }
    __syncthreads();
    #pragma unroll
    for (int rr = 0; rr < 4; ++rr) {
        int r = r0 + rr * 8;
        dst[(size_t)(n0 + r) * Mpad + m0 + c] = f2bf(tile[c][r]);
    }
}

// ---------------- FUSED conv+pool+GEMM1: block = 4 residues, 512 threads ----------------
// Abuf[128][512] bf16 (128 KB LDS), XOR-swizzled (col ^ ((row&7)<<3)) for conflict-free
// ds_read_b128. K=1024 (existing W1T layout) in 2 chunks of 512 cols. B read global->reg
// (W1T L2-resident). Epilogue staged through Abuf for contiguous 64 KB y1 store.
__global__ __launch_bounds__(512) void conv_gemm1f(
        const float* __restrict__ cat,
        const float* __restrict__ c1w, const float* __restrict__ c1b,
        const float* __restrict__ pa_p,
        const float* __restrict__ c2w, const float* __restrict__ c2b,
        const float* __restrict__ c3w, const float* __restrict__ c3b,
        const unsigned short* __restrict__ W1T, const float* __restrict__ b1v,
        unsigned short* __restrict__ y1) {
    __shared__ unsigned short Abuf[128 * 512];
    int t = threadIdx.x;
    int l0 = blockIdx.x * 4;
    int w = t >> 6, lane = t & 63;
    int wr = w >> 2, wc = w & 3;                 // 2 x 4 wave grid, 64x64 each
    int arow = lane & 15, kgrp = lane >> 4;

    // conv mapping: wave-uniform (res, half); lanes = d-pairs
    int res = t >> 7, half = (t >> 6) & 1, dp = lane;
    bool act = dp < 54;
    int d0 = dp * 2;
    float pa = pa_p[0];
    float colA[WIN], colB[WIN];
    if (act) {
        const float* cr = cat + (size_t)(l0 + res) * 756;
        #pragma unroll
        for (int h = 0; h < WIN; ++h) {
            colA[h] = cr[h * 108 + d0];
            colB[h] = cr[h * 108 + d0 + 1];
        }
    }
    f32x4 acc[4][4];
    #pragma unroll
    for (int mi = 0; mi < 4; ++mi)
        #pragma unroll
        for (int ni = 0; ni < 4; ++ni) acc[mi][ni] = (f32x4)(0.f);

    // ================= chunk 0: K cols 0..511 (b1 p0..3 full + p4 d0<80) =================
    if (act) {
        for (int c = half * 16; c < half * 16 + 16; ++c) {   // wave-uniform -> scalar weights
            int row = res * 32 + c;
            float w0 = c1w[c * 3], w1 = c1w[c * 3 + 1], w2 = c1w[c * 3 + 2];
            float bb = c1b[c];
            float vA[WIN], vB[WIN];
            #pragma unroll
            for (int h = 0; h < WIN; ++h) {
                float sA = bb, sB = bb;
                if (h >= 1) { sA = fmaf(w0, colA[h - 1], sA); sB = fmaf(w0, colB[h - 1], sB); }
                sA = fmaf(w1, colA[h], sA); sB = fmaf(w1, colB[h], sB);
                if (h <= 5) { sA = fmaf(w2, colA[h + 1], sA); sB = fmaf(w2, colB[h + 1], sB); }
                vA[h] = sA >= 0.f ? sA : pa * sA;
                vB[h] = sB >= 0.f ? sB : pa * sB;
            }
            #pragma unroll
            for (int p = 0; p < 5; ++p) {
                int col = p * 108 + d0;
                if (col < 512) {                 // p<4 always; p==4 only d0<80
                    unsigned int ua = f2bf(fmaxf(fmaxf(vA[p], vA[p + 1]), vA[p + 2]));
                    unsigned int ub = f2bf(fmaxf(fmaxf(vB[p], vB[p + 1]), vB[p + 2]));
                    *(unsigned int*)&Abuf[row * 512 + (col ^ ((row & 7) << 3))] = ua | (ub << 16);
                }
            }
        }
    }
    __syncthreads();
    #pragma unroll 1
    for (int ks = 0; ks < 8; ++ks) {
        #pragma unroll
        for (int kk = 0; kk < 2; ++kk) {
            int G = ks * 8 + kk * 4 + kgrp;
            bf16x8 af[4], bfr[4];
            #pragma unroll
            for (int ni = 0; ni < 4; ++ni) {
                int n = wc * 64 + ni * 16 + arow;
                bfr[ni] = *(const bf16x8*)&W1T[(size_t)n * 1024 + G * 8];
            }
            #pragma unroll
            for (int mi = 0; mi < 4; ++mi) {
                int rl = wr * 64 + mi * 16 + arow;
                af[mi] = *(const bf16x8*)&Abuf[rl * 512 + ((G ^ (rl & 7)) << 3)];
            }
            #pragma unroll
            for (int mi = 0; mi < 4; ++mi)
                #pragma unroll
                for (int ni = 0; ni < 4; ++ni)
                    acc[mi][ni] = __builtin_amdgcn_mfma_f32_16x16x32_bf16(af[mi], bfr[ni], acc[mi][ni], 0, 0, 0);
        }
    }
    __syncthreads();
    // ================= chunk 1: K cols 512..1023 (b1 p4 tail | b2 | b3 | pad) ============
    // local col: b1 p4 (d0>=80) -> d0-80; b2 p -> 28+p*108+d0; b3 -> 352+d0; pad 460..511
    for (int i = t; i < 128 * 26; i += 512) {
        int row = i / 26, q = i - (i / 26) * 26;
        int col = 460 + q * 2;
        *(unsigned int*)&Abuf[row * 512 + (col ^ ((row & 7) << 3))] = 0u;
    }
    if (act) {
        for (int c = half * 16; c < half * 16 + 16; ++c) {
            int row = res * 32 + c;
            if (d0 >= 80) {   // b1 p4 tail: recompute k=3 prelu conv for h=4..6
                float w0 = c1w[c * 3], w1 = c1w[c * 3 + 1], w2 = c1w[c * 3 + 2];
                float bb = c1b[c];
                float vA[3], vB[3];
                #pragma unroll
                for (int j = 0; j < 3; ++j) {
                    int h = 4 + j;
                    float sA = bb, sB = bb;
                    sA = fmaf(w0, colA[h - 1], sA); sB = fmaf(w0, colB[h - 1], sB);
                    sA = fmaf(w1, colA[h], sA);     sB = fmaf(w1, colB[h], sB);
                    if (h <= 5) { sA = fmaf(w2, colA[h + 1], sA); sB = fmaf(w2, colB[h + 1], sB); }
                    vA[j] = sA >= 0.f ? sA : pa * sA;
                    vB[j] = sB >= 0.f ? sB : pa * sB;
                }
                unsigned int ua = f2bf(fmaxf(fmaxf(vA[0], vA[1]), vA[2]));
                unsigned int ub = f2bf(fmaxf(fmaxf(vB[0], vB[1]), vB[2]));
                int col = d0 - 80;
                *(unsigned int*)&Abuf[row * 512 + (col ^ ((row & 7) << 3))] = ua | (ub << 16);
            }
            {   // branch 2: k=5, relu, pool5 -> 3 outputs at 28+p*108+d0
                float wg[5], bb = c2b[c];
                #pragma unroll
                for (int x = 0; x < 5; ++x) wg[x] = c2w[c * 5 + x];
                float vA[WIN], vB[WIN];
                #pragma unroll
                for (int h = 0; h < WIN; ++h) {
                    float sA = bb, sB = bb;
                    #pragma unroll
                    for (int x = 0; x < 5; ++x) {
                        int hh = h + x - 2;
                        if (hh >= 0 && hh <= 6) {
                            sA = fmaf(wg[x], colA[hh], sA);
                            sB = fmaf(wg[x], colB[hh], sB);
                        }
                    }
                    vA[h] = fmaxf(sA, 0.f);
                    vB[h] = fmaxf(sB, 0.f);
                }
                #pragma unroll
                for (int p = 0; p < 3; ++p) {
                    float ma = vA[p], mb = vB[p];
                    #pragma unroll
                    for (int r = 1; r < 5; ++r) { ma = fmaxf(ma, vA[p + r]); mb = fmaxf(mb, vB[p + r]); }
                    unsigned int ua = f2bf(ma), ub = f2bf(mb);
                    int col = 28 + p * 108 + d0;
                    *(unsigned int*)&Abuf[row * 512 + (col ^ ((row & 7) << 3))] = ua | (ub << 16);
                }
            }
            {   // branch 3: k=7, relu, pool7 -> 1 output at 352+d0
                float wg[7], bb = c3b[c];
                #pragma unroll
                for (int x = 0; x < 7; ++x) wg[x] = c3w[c * 7 + x];
                float ma = 0.f, mb = 0.f;
                #pragma unroll
                for (int h = 0; h < WIN; ++h) {
                    float sA = bb, sB = bb;
                    #pragma unroll
                    for (int x = 0; x < 7; ++x) {
                        int hh = h + x - 3;
                        if (hh >= 0 && hh <= 6) {
                            sA = fmaf(wg[x], colA[hh], sA);
                            sB = fmaf(wg[x], colB[hh], sB);
                        }
                    }
                    ma = fmaxf(ma, sA);
                    mb = fmaxf(mb, sB);
                }
                unsigned int ua = f2bf(fmaxf(ma, 0.f)), ub = f2bf(fmaxf(mb, 0.f));
                int col = 352 + d0;
                *(unsigned int*)&Abuf[row * 512 + (col ^ ((row & 7) << 3))] = ua | (ub << 16);
            }
        }
    }
    __syncthreads();
    #pragma unroll 1
    for (int ks = 0; ks < 8; ++ks) {
        #pragma unroll
        for (int kk = 0; kk < 2; ++kk) {
            int G = ks * 8 + kk * 4 + kgrp;
            bf16x8 af[4], bfr[4];
            #pragma unroll
            for (int ni = 0; ni < 4; ++ni) {
                int n = wc * 64 + ni * 16 + arow;
                bfr[ni] = *(const bf16x8*)&W1T[(size_t)n * 1024 + 512 + G * 8];
            }
            #pragma unroll
            for (int mi = 0; mi < 4; ++mi) {
                int rl = wr * 64 + mi * 16 + arow;
                af[mi] = *(const bf16x8*)&Abuf[rl * 512 + ((G ^ (rl & 7)) << 3)];
            }
            #pragma unroll
            for (int mi = 0; mi < 4; ++mi)
                #pragma unroll
                for (int ni = 0; ni < 4; ++ni)
                    acc[mi][ni] = __builtin_amdgcn_mfma_f32_16x16x32_bf16(af[mi], bfr[ni], acc[mi][ni], 0, 0, 0);
        }
    }
    __syncthreads();
    // ================= epilogue: C -> LDS [128][256] -> contiguous 64 KB store ===========
    #pragma unroll
    for (int ni = 0; ni < 4; ++ni) {
        int n = wc * 64 + ni * 16 + arow;
        float bv = b1v[n];
        #pragma unroll
        for (int mi = 0; mi < 4; ++mi)
            #pragma unroll
            for (int r = 0; r < 4; ++r) {
                int row = wr * 64 + mi * 16 + kgrp * 4 + r;
                Abuf[row * 256 + n] = f2bf(acc[mi][ni][r] + bv);
            }
    }
    __syncthreads();
    unsigned short* dst = y1 + (size_t)blockIdx.x * 32768;
    #pragma unroll
    for (int i = 0; i < 8; ++i) {
        int e = (i * 512 + t) * 8;
        *(ushort8v*)&dst[e] = *(const ushort8v*)&Abuf[e];
    }
}

// ---------------- 8-wave tiled MFMA GEMM, global_load_lds staging, C[128x256]/block ----------------
// (used for GEMM2) LDS linear; XOR swizzle applied to per-lane GLOBAL source column.
template<bool EPI_BF16, int ZBITS>
__global__ __launch_bounds__(512) void gemm_tile8(
        const unsigned short* __restrict__ A, long lda,
        const unsigned short* __restrict__ B, long ldb,
        int nk, const float* __restrict__ bias,
        unsigned short* __restrict__ outB, float* __restrict__ outF,
        long outRowBase) {
    __shared__ unsigned short ldsA[128 * 64];
    __shared__ unsigned short ldsB[256 * 64];
    int t = threadIdx.x, w = t >> 6, lane = t & 63;
    int bid = blockIdx.x;
    int z = bid & ((1 << ZBITS) - 1);
    long m0 = (long)(bid >> ZBITS) * 128;
    long koff = (long)z * (long)nk * 64;
    A += koff; B += koff;
    int wr = w >> 2, wc = w & 3;
    int arow = lane & 15, kgrp = lane >> 4;
    int ra = lane >> 3, cc = lane & 7;
    int csw = (cc ^ ra) * 8;

    const unsigned short* gA[2]; const unsigned short* gB[4];
    unsigned short* dA[2]; unsigned short* dB[4];
    #pragma unroll
    for (int j = 0; j < 2; ++j) {
        int rbase = j * 64 + w * 8;
        gA[j] = A + (size_t)(m0 + rbase + ra) * lda + csw;
        dA[j] = &ldsA[rbase * 64];
    }
    #pragma unroll
    for (int j = 0; j < 4; ++j) {
        int rbase = j * 64 + w * 8;
        gB[j] = B + (size_t)(rbase + ra) * ldb + csw;
        dB[j] = &ldsB[rbase * 64];
    }
    f32x4 acc[4][4];
    #pragma unroll
    for (int mi = 0; mi < 4; ++mi)
        #pragma unroll
        for (int ni = 0; ni < 4; ++ni) acc[mi][ni] = (f32x4)(0.f);

    for (int ks = 0; ks < nk; ++ks) {
        #pragma unroll
        for (int j = 0; j < 2; ++j) gload16(gA[j] + ks * 64, dA[j]);
        #pragma unroll
        for (int j = 0; j < 4; ++j) gload16(gB[j] + ks * 64, dB[j]);
        __syncthreads();
        #pragma unroll
        for (int kk = 0; kk < 2; ++kk) {
            int chunk = kk * 4 + kgrp;
            bf16x8 af[4], bfr[4];
            #pragma unroll
            for (int mi = 0; mi < 4; ++mi) {
                int rl = wr * 64 + mi * 16 + arow;
                af[mi] = *(const bf16x8*)&ldsA[rl * 64 + ((chunk ^ (rl & 7)) * 8)];
            }
            #pragma unroll
            for (int ni = 0; ni < 4; ++ni) {
                int rl = wc * 64 + ni * 16 + arow;
                bfr[ni] = *(const bf16x8*)&ldsB[rl * 64 + ((chunk ^ (rl & 7)) * 8)];
            }
            #pragma unroll
            for (int mi = 0; mi < 4; ++mi)
                #pragma unroll
                for (int ni = 0; ni < 4; ++ni)
                    acc[mi][ni] = __builtin_amdgcn_mfma_f32_16x16x32_bf16(af[mi], bfr[ni], acc[mi][ni], 0, 0, 0);
        }
        __syncthreads();
    }
    #pragma unroll
    for (int ni = 0; ni < 4; ++ni) {
        int n = wc * 64 + ni * 16 + arow;
        float bv = EPI_BF16 ? bias[n] : 0.f;
        #pragma unroll
        for (int mi = 0; mi < 4; ++mi)
            #pragma unroll
            for (int r = 0; r < 4; ++r) {
                long m = m0 + wr * 64 + mi * 16 + kgrp * 4 + r;
                if (EPI_BF16)
                    outB[(outRowBase + m) * 256 + n] = f2bf(acc[mi][ni][r] + bv);
                else
                    outF[((long)z * 2048 + m) * 256 + n] = acc[mi][ni][r];
            }
    }
}

// ---------------- reduce partials + bias + leaky ----------------
__global__ __launch_bounds__(256) void reduce2(const float* __restrict__ part,
                                               const float* __restrict__ b2v,
                                               float* __restrict__ out) {
    int l = blockIdx.x, n = threadIdx.x;
    float sum = b2v[n];
    #pragma unroll
    for (int s = 0; s < 8; ++s) sum += part[((size_t)s * 2048 + l) * 256 + n];
    out[(size_t)l * 256 + n] = sum >= 0.f ? sum : 0.01f * sum;
}

extern "C" void kernel_launch(void* const* d_in, const int* in_sizes, int n_in,
                              void* d_out, int out_size, void* d_ws, size_t ws_size,
                              hipStream_t stream) {
    const float* beft = (const float*)d_in[0];
    const float* Wb  = (const float*)d_in[4];
    const float* bb  = (const float*)d_in[5];
    const float* g1  = (const float*)d_in[6];
    const float* b1  = (const float*)d_in[7];
    const float* g2  = (const float*)d_in[8];
    const float* b2  = (const float*)d_in[9];
    const float* c1w = (const float*)d_in[10];
    const float* c1b = (const float*)d_in[11];
    const float* pa  = (const float*)d_in[12];
    const float* c2w = (const float*)d_in[13];
    const float* c2b = (const float*)d_in[14];
    const float* c3w = (const float*)d_in[15];
    const float* c3b = (const float*)d_in[16];
    const float* W1  = (const float*)d_in[17];
    const float* b1v = (const float*)d_in[18];
    const float* W2  = (const float*)d_in[19];
    const float* b2v = (const float*)d_in[20];
    float* out = (float*)d_out;
    char* ws = (char*)d_ws;

    // layout (overlays are temporally disjoint):
    float*          f    = (float*)(ws + 0);                   // 432,000 B [dead after attn]
    float*          cat  = (float*)(ws + 524288);              // 6,048,000 B [dead after conv_gemm1f]
    unsigned short* W1T  = (unsigned short*)(ws + 8388608);    // 524,288 B
    unsigned short* W2T  = (unsigned short*)(ws + 8912896);    // 4,194,304 B
    unsigned short* y1   = (unsigned short*)(ws + 13107200);   // 33,554,432 B
    unsigned short* A2   = (unsigned short*)(ws + 13107200);   // 12,582,912 B [bert phase, overlays y1]
    unsigned short* B2T  = (unsigned short*)(ws + 25690112);   // 393,216 B    [bert phase, within y1]
    float*          bpart= (float*)(ws + 46661632);            // 2,097,152 B  [bert phase]
    float*          part = (float*)(ws + 46661632);            // 16,777,216 B [gemm2 phase]

    split_beft<<<2048, 256, 0, stream>>>(beft, A2);
    b2t_build<<<768, 256, 0, stream>>>(Wb, B2T);
    bert_mfma<<<dim3(16, 4), 256, 0, stream>>>(A2, B2T, bpart);
    bert_reduce<<<L_RES, 64, 0, stream>>>(bpart, bb, f);
    window_attn4<<<500, 256, 0, stream>>>(f, g1, b1, g2, b2, cat);
    transpose_to_bf16<<<dim3(32, 8), 256, 0, stream>>>(W1, W1T, 972, 256, 1024);
    transpose_to_bf16<<<dim3(256, 8), 256, 0, stream>>>(W2, W2T, 8192, 256, 8192);

    conv_gemm1f<<<500, 512, 0, stream>>>(cat, c1w, c1b, pa, c2w, c2b, c3w, c3b,
                                         W1T, b1v, y1);
    gemm_tile8<false, 3><<<128, 512, 0, stream>>>(
        y1, 8192, W2T, 8192, 16, nullptr, nullptr, part, 0);
    reduce2<<<L_RES, 256, 0, stream>>>(part, b2v, out);
}

// Round 11
// 169.900 us; speedup vs baseline: 1.0955x; 1.0955x over previous
//
#include <hip/hip_runtime.h>

#define L_RES 2000
#define DF 54
#define WIN 7

typedef short bf16x8 __attribute__((ext_vector_type(8)));
typedef float f32x4 __attribute__((ext_vector_type(4)));
typedef unsigned short ushort8v __attribute__((ext_vector_type(8)));

__device__ __forceinline__ unsigned short f2bf(float f) {
    unsigned int u = __float_as_uint(f);
    unsigned int r = (u + 0x7FFFu + ((u >> 16) & 1u)) >> 16;
    return (unsigned short)r;
}
__device__ __forceinline__ float bf2f(unsigned short h) {
    return __uint_as_float(((unsigned int)h) << 16);
}
// async global->LDS, 16B per lane; LDS dest = wave-uniform base + lane*16
__device__ __forceinline__ void gload16(const unsigned short* g, unsigned short* l) {
    __builtin_amdgcn_global_load_lds(
        (const __attribute__((address_space(1))) void*)g,
        (__attribute__((address_space(3))) void*)l, 16, 0, 0);
}

// ---------------- bert stage a: split beft into A2 = [hi | lo | hi], K=3072, 2048 rows ----------------
__global__ __launch_bounds__(256) void split_beft(const float* __restrict__ beft,
                                                  unsigned short* __restrict__ A2) {
    int l = blockIdx.x;
    int t = threadIdx.x;
    unsigned short* row = A2 + (size_t)l * 3072;
    for (int k = t; k < 1024; k += 256) {
        unsigned short hi = 0, lo = 0;
        if (l < L_RES) {
            float x = beft[(size_t)l * 1024 + k];
            hi = f2bf(x);
            lo = f2bf(x - bf2f(hi));
        }
        row[k] = hi;
        row[1024 + k] = lo;
        row[2048 + k] = hi;
    }
}

// ---------------- bert stage b: B2T[64][3072]: segs {hi,hi,lo} of Wb^T ----------------
__global__ __launch_bounds__(256) void b2t_build(const float* __restrict__ Wb,
                                                 unsigned short* __restrict__ B2T) {
    int idx = blockIdx.x * 256 + threadIdx.x;   // 64*3072 = 196608
    int n = idx / 3072, col = idx % 3072;
    int seg = col >> 10, k = col & 1023;
    unsigned short r = 0;
    if (n < DF) {
        float v = Wb[(size_t)k * DF + n];
        unsigned short hi = f2bf(v);
        r = (seg < 2) ? hi : f2bf(v - bf2f(hi));
    }
    B2T[idx] = r;
}

// ---------------- bert stage c: MFMA GEMM M=2048 N=64, K-split z=4 -> fp32 partials ----------------
__global__ __launch_bounds__(256) void bert_mfma(const unsigned short* __restrict__ A2,
                                                 const unsigned short* __restrict__ B2T,
                                                 float* __restrict__ bpart) {
    __shared__ unsigned short ldsA[128 * 64];
    __shared__ unsigned short ldsB[64 * 64];
    int t = threadIdx.x, w = t >> 6, lane = t & 63;
    int m0 = blockIdx.x * 128;
    int z = blockIdx.y;                       // 4 K-slices of 768
    long koff = (long)z * 768;
    int wr = w >> 1, wc = w & 1;
    int arow = lane & 15, kgrp = lane >> 4;

    const unsigned short* aS[4]; const unsigned short* bS[2];
    int aD[4], bD[2];
    #pragma unroll
    for (int j = 0; j < 4; ++j) {
        int s = j * 256 + t, r = s >> 3, c = s & 7;
        aS[j] = A2 + koff + (size_t)(m0 + r) * 3072 + c * 8;
        aD[j] = r * 64 + ((c ^ (r & 7)) * 8);
    }
    #pragma unroll
    for (int j = 0; j < 2; ++j) {
        int s = j * 256 + t, r = s >> 3, c = s & 7;
        bS[j] = B2T + koff + (size_t)r * 3072 + c * 8;
        bD[j] = r * 64 + ((c ^ (r & 7)) * 8);
    }
    f32x4 acc[4][2];
    #pragma unroll
    for (int mi = 0; mi < 4; ++mi)
        #pragma unroll
        for (int ni = 0; ni < 2; ++ni) acc[mi][ni] = (f32x4)(0.f);

    ushort8v va[4], vb[2];
    #pragma unroll
    for (int j = 0; j < 4; ++j) va[j] = *(const ushort8v*)(aS[j]);
    #pragma unroll
    for (int j = 0; j < 2; ++j) vb[j] = *(const ushort8v*)(bS[j]);

    for (int ks = 0; ks < 12; ++ks) {
        __syncthreads();
        #pragma unroll
        for (int j = 0; j < 4; ++j) *(ushort8v*)&ldsA[aD[j]] = va[j];
        #pragma unroll
        for (int j = 0; j < 2; ++j) *(ushort8v*)&ldsB[bD[j]] = vb[j];
        __syncthreads();
        if (ks + 1 < 12) {
            #pragma unroll
            for (int j = 0; j < 4; ++j) va[j] = *(const ushort8v*)(aS[j] + (ks + 1) * 64);
            #pragma unroll
            for (int j = 0; j < 2; ++j) vb[j] = *(const ushort8v*)(bS[j] + (ks + 1) * 64);
        }
        #pragma unroll
        for (int kk = 0; kk < 2; ++kk) {
            int chunk = kk * 4 + kgrp;
            bf16x8 af[4], bfr[2];
            #pragma unroll
            for (int mi = 0; mi < 4; ++mi) {
                int rl = wr * 64 + mi * 16 + arow;
                af[mi] = *(const bf16x8*)&ldsA[rl * 64 + ((chunk ^ (rl & 7)) * 8)];
            }
            #pragma unroll
            for (int ni = 0; ni < 2; ++ni) {
                int rl = wc * 32 + ni * 16 + arow;
                bfr[ni] = *(const bf16x8*)&ldsB[rl * 64 + ((chunk ^ (rl & 7)) * 8)];
            }
            #pragma unroll
            for (int mi = 0; mi < 4; ++mi)
                #pragma unroll
                for (int ni = 0; ni < 2; ++ni)
                    acc[mi][ni] = __builtin_amdgcn_mfma_f32_16x16x32_bf16(af[mi], bfr[ni], acc[mi][ni], 0, 0, 0);
        }
    }
    #pragma unroll
    for (int ni = 0; ni < 2; ++ni) {
        int n = wc * 32 + ni * 16 + arow;
        #pragma unroll
        for (int mi = 0; mi < 4; ++mi)
            #pragma unroll
            for (int r = 0; r < 4; ++r) {
                int m = m0 + wr * 64 + mi * 16 + kgrp * 4 + r;
                bpart[((size_t)z * 2048 + m) * 64 + n] = acc[mi][ni][r];
            }
    }
}

// ---------------- bert stage d: reduce 4 partials + bias -> f (L,54) ----------------
__global__ __launch_bounds__(64) void bert_reduce(const float* __restrict__ bpart,
                                                  const float* __restrict__ bb,
                                                  float* __restrict__ f) {
    int l = blockIdx.x, n = threadIdx.x;
    if (n < DF) {
        float s = bb[n];
        #pragma unroll
        for (int z = 0; z < 4; ++z) s += bpart[((size_t)z * 2048 + l) * 64 + n];
        f[(size_t)l * DF + n] = s;
    }
}

// ---------------- window gather + attn x2 + concat, 4 residues (1 wave each) ----------------
__device__ __forceinline__ void attn_layer_w(const float (*in)[DF], float (*out)[DF],
                                             float (*s)[WIN][WIN],
                                             const float* __restrict__ g,
                                             const float* __restrict__ b,
                                             float* mm, float* vv, int lane) {
    for (int idx = lane; idx < 3 * WIN * WIN; idx += 64) {
        int h = idx / 49, r = idx % 49, q = r / WIN, k = r % WIN;
        float sum = 0.f;
        #pragma unroll
        for (int d = 0; d < 18; ++d) sum = fmaf(in[q][h * 18 + d], in[k][h * 18 + d], sum);
        s[h][q][k] = sum;
    }
    __syncthreads();
    for (int idx = lane; idx < 3 * WIN; idx += 64) {
        int h = idx / WIN, q = idx % WIN;
        float mx = s[h][q][0];
        #pragma unroll
        for (int k = 1; k < WIN; ++k) mx = fmaxf(mx, s[h][q][k]);
        float e[WIN], sum = 0.f;
        #pragma unroll
        for (int k = 0; k < WIN; ++k) { e[k] = expf(s[h][q][k] - mx); sum += e[k]; }
        float inv = 1.f / sum;
        #pragma unroll
        for (int k = 0; k < WIN; ++k) s[h][q][k] = e[k] * inv;
    }
    __syncthreads();
    for (int idx = lane; idx < WIN * DF; idx += 64) {
        int q = idx / DF, c = idx % DF, h = c / 18;
        float sum = 0.f;
        #pragma unroll
        for (int k = 0; k < WIN; ++k) sum = fmaf(s[h][q][k], in[k][c], sum);
        out[q][c] = sum;
    }
    __syncthreads();
    for (int q = lane; q < WIN; q += 64) {
        float m = 0.f;
        for (int c = 0; c < DF; ++c) m += out[q][c];
        m *= (1.f / DF);
        float v = 0.f;
        for (int c = 0; c < DF; ++c) { float d0 = out[q][c] - m; v = fmaf(d0, d0, v); }
        v *= (1.f / DF);
        mm[q] = m; vv[q] = rsqrtf(v + 1e-5f);
    }
    __syncthreads();
    for (int idx = lane; idx < WIN * DF; idx += 64) {
        int q = idx / DF, c = idx % DF;
        out[q][c] = (out[q][c] - mm[q]) * vv[q] * g[c] + b[c];
    }
    __syncthreads();
}

__global__ __launch_bounds__(256) void window_attn4(const float* __restrict__ f,
                                                    const float* __restrict__ g1,
                                                    const float* __restrict__ b1,
                                                    const float* __restrict__ g2,
                                                    const float* __restrict__ b2,
                                                    float* __restrict__ cat) {
    int wv = threadIdx.x >> 6, lane = threadIdx.x & 63;
    int l = blockIdx.x * 4 + wv;
    __shared__ float w[4][WIN][DF], o1[4][WIN][DF], o2[4][WIN][DF];
    __shared__ float s[4][3][WIN][WIN];
    __shared__ float mm[4][WIN], vvv[4][WIN];
    bool boundary = (l <= WIN) || (l + WIN >= L_RES);
    for (int idx = lane; idx < WIN * DF; idx += 64) {
        int j = idx / DF, d = idx % DF;
        w[wv][j][d] = boundary ? (j == 0 ? f[(size_t)l * DF + d] : 0.f)
                               : f[(size_t)(l - 4 + j) * DF + d];
    }
    __syncthreads();
    attn_layer_w(w[wv], o1[wv], s[wv], g1, b1, mm[wv], vvv[wv], lane);
    attn_layer_w(o1[wv], o2[wv], s[wv], g2, b2, mm[wv], vvv[wv], lane);
    for (int idx = lane; idx < WIN * DF; idx += 64) {
        int j = idx / DF, d = idx % DF;
        cat[(size_t)l * 756 + j * 108 + d] = w[wv][j][d];
        cat[(size_t)l * 756 + j * 108 + DF + d] = o2[wv][j][d];
    }
}

// ---------------- transpose + f32->bf16: dst[n][m], rows m>=M zero-padded ----------------
__global__ __launch_bounds__(256) void transpose_to_bf16(const float* __restrict__ src,
                                                         unsigned short* __restrict__ dst,
                                                         int M, int N, int Mpad) {
    __shared__ float tile[32][33];
    int m0 = blockIdx.x * 32, n0 = blockIdx.y * 32;
    int c = threadIdx.x % 32, r0 = threadIdx.x / 32;
    #pragma unroll
    for (int rr = 0; rr < 4; ++rr) {
        int r = r0 + rr * 8, m = m0 + r;
        tile[r][c] = (m < M) ? src[(size_t)m * N + n0 + c] : 0.f;
    }
    __syncthreads();
    #pragma unroll
    for (int rr = 0; rr < 4; ++rr) {
        int r = r0 + rr * 8;
        dst[(size_t)(n0 + r) * Mpad + m0 + c] = f2bf(tile[c][r]);
    }
}

// ---------------- FUSED conv+pool+GEMM1 v2: block = 2 residues, 256 threads, 64 KB LDS ----------------
// Abuf[64][512] bf16, XOR-swizzled (col ^ ((row&7)<<3)). K=1024 in 2 chunks of 512.
// 2 blocks/CU -> conv phase of one block overlaps MFMA phase of the CU-neighbor.
// B (W1T, 512 KB) read global->reg, L2-resident. Epilogue stores acc directly.
__global__ __launch_bounds__(256) void conv_gemm1f(
        const float* __restrict__ cat,
        const float* __restrict__ c1w, const float* __restrict__ c1b,
        const float* __restrict__ pa_p,
        const float* __restrict__ c2w, const float* __restrict__ c2b,
        const float* __restrict__ c3w, const float* __restrict__ c3b,
        const unsigned short* __restrict__ W1T, const float* __restrict__ b1v,
        unsigned short* __restrict__ y1) {
    __shared__ unsigned short Abuf[64 * 512];
    int t = threadIdx.x;
    int l0 = blockIdx.x * 2;
    int w = t >> 6, lane = t & 63;
    int wc = w;                                   // 1 x 4 wave grid, each 64 x 64
    int arow = lane & 15, kgrp = lane >> 4;

    // conv mapping: wave-uniform (res, half); lanes = d-pairs
    int res = t >> 7, half = (t >> 6) & 1, dp = lane;
    bool act = dp < 54;
    int d0 = dp * 2;
    float pa = pa_p[0];
    float colA[WIN], colB[WIN];
    if (act) {
        const float* cr = cat + (size_t)(l0 + res) * 756;
        #pragma unroll
        for (int h = 0; h < WIN; ++h) {
            colA[h] = cr[h * 108 + d0];
            colB[h] = cr[h * 108 + d0 + 1];
        }
    }
    f32x4 acc[4][4];
    #pragma unroll
    for (int mi = 0; mi < 4; ++mi)
        #pragma unroll
        for (int ni = 0; ni < 4; ++ni) acc[mi][ni] = (f32x4)(0.f);

    // ================= chunk 0: K cols 0..511 (b1 p0..3 full + p4 d0<80) =================
    if (act) {
        for (int c = half * 16; c < half * 16 + 16; ++c) {   // wave-uniform -> scalar weights
            int row = res * 32 + c;
            float w0 = c1w[c * 3], w1 = c1w[c * 3 + 1], w2 = c1w[c * 3 + 2];
            float bb = c1b[c];
            float vA[WIN], vB[WIN];
            #pragma unroll
            for (int h = 0; h < WIN; ++h) {
                float sA = bb, sB = bb;
                if (h >= 1) { sA = fmaf(w0, colA[h - 1], sA); sB = fmaf(w0, colB[h - 1], sB); }
                sA = fmaf(w1, colA[h], sA); sB = fmaf(w1, colB[h], sB);
                if (h <= 5) { sA = fmaf(w2, colA[h + 1], sA); sB = fmaf(w2, colB[h + 1], sB); }
                vA[h] = sA >= 0.f ? sA : pa * sA;
                vB[h] = sB >= 0.f ? sB : pa * sB;
            }
            #pragma unroll
            for (int p = 0; p < 5; ++p) {
                int col = p * 108 + d0;
                if (col < 512) {                 // p<4 always; p==4 only d0<80
                    unsigned int ua = f2bf(fmaxf(fmaxf(vA[p], vA[p + 1]), vA[p + 2]));
                    unsigned int ub = f2bf(fmaxf(fmaxf(vB[p], vB[p + 1]), vB[p + 2]));
                    *(unsigned int*)&Abuf[row * 512 + (col ^ ((row & 7) << 3))] = ua | (ub << 16);
                }
            }
        }
    }
    __syncthreads();
    #pragma unroll 1
    for (int ks = 0; ks < 8; ++ks) {
        #pragma unroll
        for (int kk = 0; kk < 2; ++kk) {
            int G = ks * 8 + kk * 4 + kgrp;
            bf16x8 af[4], bfr[4];
            #pragma unroll
            for (int ni = 0; ni < 4; ++ni) {
                int n = wc * 64 + ni * 16 + arow;
                bfr[ni] = *(const bf16x8*)&W1T[(size_t)n * 1024 + G * 8];
            }
            #pragma unroll
            for (int mi = 0; mi < 4; ++mi) {
                int rl = mi * 16 + arow;
                af[mi] = *(const bf16x8*)&Abuf[rl * 512 + ((G ^ (rl & 7)) << 3)];
            }
            #pragma unroll
            for (int mi = 0; mi < 4; ++mi)
                #pragma unroll
                for (int ni = 0; ni < 4; ++ni)
                    acc[mi][ni] = __builtin_amdgcn_mfma_f32_16x16x32_bf16(af[mi], bfr[ni], acc[mi][ni], 0, 0, 0);
        }
    }
    __syncthreads();
    // ================= chunk 1: K cols 512..1023 (b1 p4 tail | b2 | b3 | pad) ============
    // local col: b1 p4 (d0>=80) -> d0-80; b2 p -> 28+p*108+d0; b3 -> 352+d0; pad 460..511
    for (int i = t; i < 64 * 26; i += 256) {
        int row = i / 26, q = i - (i / 26) * 26;
        int col = 460 + q * 2;
        *(unsigned int*)&Abuf[row * 512 + (col ^ ((row & 7) << 3))] = 0u;
    }
    if (act) {
        for (int c = half * 16; c < half * 16 + 16; ++c) {
            int row = res * 32 + c;
            if (d0 >= 80) {   // b1 p4 tail: recompute k=3 prelu conv for h=4..6
                float w0 = c1w[c * 3], w1 = c1w[c * 3 + 1], w2 = c1w[c * 3 + 2];
                float bb = c1b[c];
                float vA[3], vB[3];
                #pragma unroll
                for (int j = 0; j < 3; ++j) {
                    int h = 4 + j;
                    float sA = bb, sB = bb;
                    sA = fmaf(w0, colA[h - 1], sA); sB = fmaf(w0, colB[h - 1], sB);
                    sA = fmaf(w1, colA[h], sA);     sB = fmaf(w1, colB[h], sB);
                    if (h <= 5) { sA = fmaf(w2, colA[h + 1], sA); sB = fmaf(w2, colB[h + 1], sB); }
                    vA[j] = sA >= 0.f ? sA : pa * sA;
                    vB[j] = sB >= 0.f ? sB : pa * sB;
                }
                unsigned int ua = f2bf(fmaxf(fmaxf(vA[0], vA[1]), vA[2]));
                unsigned int ub = f2bf(fmaxf(fmaxf(vB[0], vB[1]), vB[2]));
                int col = d0 - 80;
                *(unsigned int*)&Abuf[row * 512 + (col ^ ((row & 7) << 3))] = ua | (ub << 16);
            }
            {   // branch 2: k=5, relu, pool5 -> 3 outputs at 28+p*108+d0
                float wg[5], bb = c2b[c];
                #pragma unroll
                for (int x = 0; x < 5; ++x) wg[x] = c2w[c * 5 + x];
                float vA[WIN], vB[WIN];
                #pragma unroll
                for (int h = 0; h < WIN; ++h) {
                    float sA = bb, sB = bb;
                    #pragma unroll
                    for (int x = 0; x < 5; ++x) {
                        int hh = h + x - 2;
                        if (hh >= 0 && hh <= 6) {
                            sA = fmaf(wg[x], colA[hh], sA);
                            sB = fmaf(wg[x], colB[hh], sB);
                        }
                    }
                    vA[h] = fmaxf(sA, 0.f);
                    vB[h] = fmaxf(sB, 0.f);
                }
                #pragma unroll
                for (int p = 0; p < 3; ++p) {
                    float ma = vA[p], mb = vB[p];
                    #pragma unroll
                    for (int r = 1; r < 5; ++r) { ma = fmaxf(ma, vA[p + r]); mb = fmaxf(mb, vB[p + r]); }
                    unsigned int ua = f2bf(ma), ub = f2bf(mb);
                    int col = 28 + p * 108 + d0;
                    *(unsigned int*)&Abuf[row * 512 + (col ^ ((row & 7) << 3))] = ua | (ub << 16);
                }
            }
            {   // branch 3: k=7, relu, pool7 -> 1 output at 352+d0
                float wg[7], bb = c3b[c];
                #pragma unroll
                for (int x = 0; x < 7; ++x) wg[x] = c3w[c * 7 + x];
                float ma = 0.f, mb = 0.f;
                #pragma unroll
                for (int h = 0; h < WIN; ++h) {
                    float sA = bb, sB = bb;
                    #pragma unroll
                    for (int x = 0; x < 7; ++x) {
                        int hh = h + x - 3;
                        if (hh >= 0 && hh <= 6) {
                            sA = fmaf(wg[x], colA[hh], sA);
                            sB = fmaf(wg[x], colB[hh], sB);
                        }
                    }
                    ma = fmaxf(ma, sA);
                    mb = fmaxf(mb, sB);
                }
                unsigned int ua = f2bf(fmaxf(ma, 0.f)), ub = f2bf(fmaxf(mb, 0.f));
                int col = 352 + d0;
                *(unsigned int*)&Abuf[row * 512 + (col ^ ((row & 7) << 3))] = ua | (ub << 16);
            }
        }
    }
    __syncthreads();
    #pragma unroll 1
    for (int ks = 0; ks < 8; ++ks) {
        #pragma unroll
        for (int kk = 0; kk < 2; ++kk) {
            int G = ks * 8 + kk * 4 + kgrp;
            bf16x8 af[4], bfr[4];
            #pragma unroll
            for (int ni = 0; ni < 4; ++ni) {
                int n = wc * 64 + ni * 16 + arow;
                bfr[ni] = *(const bf16x8*)&W1T[(size_t)n * 1024 + 512 + G * 8];
            }
            #pragma unroll
            for (int mi = 0; mi < 4; ++mi) {
                int rl = mi * 16 + arow;
                af[mi] = *(const bf16x8*)&Abuf[rl * 512 + ((G ^ (rl & 7)) << 3)];
            }
            #pragma unroll
            for (int mi = 0; mi < 4; ++mi)
                #pragma unroll
                for (int ni = 0; ni < 4; ++ni)
                    acc[mi][ni] = __builtin_amdgcn_mfma_f32_16x16x32_bf16(af[mi], bfr[ni], acc[mi][ni], 0, 0, 0);
        }
    }
    // ================= epilogue: bias + bf16 + direct store (block range contiguous) =====
    unsigned short* dst = y1 + (size_t)blockIdx.x * 16384;
    #pragma unroll
    for (int ni = 0; ni < 4; ++ni) {
        int n = wc * 64 + ni * 16 + arow;
        float bv = b1v[n];
        #pragma unroll
        for (int mi = 0; mi < 4; ++mi)
            #pragma unroll
            for (int r = 0; r < 4; ++r) {
                int row = mi * 16 + kgrp * 4 + r;
                dst[row * 256 + n] = f2bf(acc[mi][ni][r] + bv);
            }
    }
}

// ---------------- 8-wave tiled MFMA GEMM, global_load_lds staging, C[128x256]/block ----------------
// (used for GEMM2) LDS linear; XOR swizzle applied to per-lane GLOBAL source column.
template<bool EPI_BF16, int ZBITS>
__global__ __launch_bounds__(512) void gemm_tile8(
        const unsigned short* __restrict__ A, long lda,
        const unsigned short* __restrict__ B, long ldb,
        int nk, const float* __restrict__ bias,
        unsigned short* __restrict__ outB, float* __restrict__ outF,
        long outRowBase) {
    __shared__ unsigned short ldsA[128 * 64];
    __shared__ unsigned short ldsB[256 * 64];
    int t = threadIdx.x, w = t >> 6, lane = t & 63;
    int bid = blockIdx.x;
    int z = bid & ((1 << ZBITS) - 1);
    long m0 = (long)(bid >> ZBITS) * 128;
    long koff = (long)z * (long)nk * 64;
    A += koff; B += koff;
    int wr = w >> 2, wc = w & 3;
    int arow = lane & 15, kgrp = lane >> 4;
    int ra = lane >> 3, cc = lane & 7;
    int csw = (cc ^ ra) * 8;

    const unsigned short* gA[2]; const unsigned short* gB[4];
    unsigned short* dA[2]; unsigned short* dB[4];
    #pragma unroll
    for (int j = 0; j < 2; ++j) {
        int rbase = j * 64 + w * 8;
        gA[j] = A + (size_t)(m0 + rbase + ra) * lda + csw;
        dA[j] = &ldsA[rbase * 64];
    }
    #pragma unroll
    for (int j = 0; j < 4; ++j) {
        int rbase = j * 64 + w * 8;
        gB[j] = B + (size_t)(rbase + ra) * ldb + csw;
        dB[j] = &ldsB[rbase * 64];
    }
    f32x4 acc[4][4];
    #pragma unroll
    for (int mi = 0; mi < 4; ++mi)
        #pragma unroll
        for (int ni = 0; ni < 4; ++ni) acc[mi][ni] = (f32x4)(0.f);

    for (int ks = 0; ks < nk; ++ks) {
        #pragma unroll
        for (int j = 0; j < 2; ++j) gload16(gA[j] + ks * 64, dA[j]);
        #pragma unroll
        for (int j = 0; j < 4; ++j) gload16(gB[j] + ks * 64, dB[j]);
        __syncthreads();
        #pragma unroll
        for (int kk = 0; kk < 2; ++kk) {
            int chunk = kk * 4 + kgrp;
            bf16x8 af[4], bfr[4];
            #pragma unroll
            for (int mi = 0; mi < 4; ++mi) {
                int rl = wr * 64 + mi * 16 + arow;
                af[mi] = *(const bf16x8*)&ldsA[rl * 64 + ((chunk ^ (rl & 7)) * 8)];
            }
            #pragma unroll
            for (int ni = 0; ni < 4; ++ni) {
                int rl = wc * 64 + ni * 16 + arow;
                bfr[ni] = *(const bf16x8*)&ldsB[rl * 64 + ((chunk ^ (rl & 7)) * 8)];
            }
            #pragma unroll
            for (int mi = 0; mi < 4; ++mi)
                #pragma unroll
                for (int ni = 0; ni < 4; ++ni)
                    acc[mi][ni] = __builtin_amdgcn_mfma_f32_16x16x32_bf16(af[mi], bfr[ni], acc[mi][ni], 0, 0, 0);
        }
        __syncthreads();
    }
    #pragma unroll
    for (int ni = 0; ni < 4; ++ni) {
        int n = wc * 64 + ni * 16 + arow;
        float bv = EPI_BF16 ? bias[n] : 0.f;
        #pragma unroll
        for (int mi = 0; mi < 4; ++mi)
            #pragma unroll
            for (int r = 0; r < 4; ++r) {
                long m = m0 + wr * 64 + mi * 16 + kgrp * 4 + r;
                if (EPI_BF16)
                    outB[(outRowBase + m) * 256 + n] = f2bf(acc[mi][ni][r] + bv);
                else
                    outF[((long)z * 2048 + m) * 256 + n] = acc[mi][ni][r];
            }
    }
}

// ---------------- reduce partials + bias + leaky ----------------
__global__ __launch_bounds__(256) void reduce2(const float* __restrict__ part,
                                               const float* __restrict__ b2v,
                                               float* __restrict__ out) {
    int l = blockIdx.x, n = threadIdx.x;
    float sum = b2v[n];
    #pragma unroll
    for (int s = 0; s < 8; ++s) sum += part[((size_t)s * 2048 + l) * 256 + n];
    out[(size_t)l * 256 + n] = sum >= 0.f ? sum : 0.01f * sum;
}

extern "C" void kernel_launch(void* const* d_in, const int* in_sizes, int n_in,
                              void* d_out, int out_size, void* d_ws, size_t ws_size,
                              hipStream_t stream) {
    const float* beft = (const float*)d_in[0];
    const float* Wb  = (const float*)d_in[4];
    const float* bb  = (const float*)d_in[5];
    const float* g1  = (const float*)d_in[6];
    const float* b1  = (const float*)d_in[7];
    const float* g2  = (const float*)d_in[8];
    const float* b2  = (const float*)d_in[9];
    const float* c1w = (const float*)d_in[10];
    const float* c1b = (const float*)d_in[11];
    const float* pa  = (const float*)d_in[12];
    const float* c2w = (const float*)d_in[13];
    const float* c2b = (const float*)d_in[14];
    const float* c3w = (const float*)d_in[15];
    const float* c3b = (const float*)d_in[16];
    const float* W1  = (const float*)d_in[17];
    const float* b1v = (const float*)d_in[18];
    const float* W2  = (const float*)d_in[19];
    const float* b2v = (const float*)d_in[20];
    float* out = (float*)d_out;
    char* ws = (char*)d_ws;

    // layout (overlays are temporally disjoint):
    float*          f    = (float*)(ws + 0);                   // 432,000 B [dead after attn]
    float*          cat  = (float*)(ws + 524288);              // 6,048,000 B [dead after conv_gemm1f]
    unsigned short* W1T  = (unsigned short*)(ws + 8388608);    // 524,288 B
    unsigned short* W2T  = (unsigned short*)(ws + 8912896);    // 4,194,304 B
    unsigned short* y1   = (unsigned short*)(ws + 13107200);   // 33,554,432 B
    unsigned short* A2   = (unsigned short*)(ws + 13107200);   // 12,582,912 B [bert phase, overlays y1]
    unsigned short* B2T  = (unsigned short*)(ws + 25690112);   // 393,216 B    [bert phase, within y1]
    float*          bpart= (float*)(ws + 46661632);            // 2,097,152 B  [bert phase]
    float*          part = (float*)(ws + 46661632);            // 16,777,216 B [gemm2 phase]

    split_beft<<<2048, 256, 0, stream>>>(beft, A2);
    b2t_build<<<768, 256, 0, stream>>>(Wb, B2T);
    bert_mfma<<<dim3(16, 4), 256, 0, stream>>>(A2, B2T, bpart);
    bert_reduce<<<L_RES, 64, 0, stream>>>(bpart, bb, f);
    window_attn4<<<500, 256, 0, stream>>>(f, g1, b1, g2, b2, cat);
    transpose_to_bf16<<<dim3(32, 8), 256, 0, stream>>>(W1, W1T, 972, 256, 1024);
    transpose_to_bf16<<<dim3(256, 8), 256, 0, stream>>>(W2, W2T, 8192, 256, 8192);

    conv_gemm1f<<<1000, 256, 0, stream>>>(cat, c1w, c1b, pa, c2w, c2b, c3w, c3b,
                                          W1T, b1v, y1);
    gemm_tile8<false, 3><<<128, 512, 0, stream>>>(
        y1, 8192, W2T, 8192, 16, nullptr, nullptr, part, 0);
    reduce2<<<L_RES, 256, 0, stream>>>(part, b2v, out);
}

// Round 12
// 152.521 us; speedup vs baseline: 1.2203x; 1.1139x over previous
//
#include <hip/hip_runtime.h>

#define L_RES 2000
#define DF 54
#define WIN 7

typedef short bf16x8 __attribute__((ext_vector_type(8)));
typedef float f32x4 __attribute__((ext_vector_type(4)));
typedef unsigned short ushort8v __attribute__((ext_vector_type(8)));

__device__ __forceinline__ unsigned short f2bf(float f) {
    unsigned int u = __float_as_uint(f);
    unsigned int r = (u + 0x7FFFu + ((u >> 16) & 1u)) >> 16;
    return (unsigned short)r;
}
__device__ __forceinline__ float bf2f(unsigned short h) {
    return __uint_as_float(((unsigned int)h) << 16);
}
// async global->LDS, 16B per lane; LDS dest = wave-uniform base + lane*16
__device__ __forceinline__ void gload16(const unsigned short* g, unsigned short* l) {
    __builtin_amdgcn_global_load_lds(
        (const __attribute__((address_space(1))) void*)g,
        (__attribute__((address_space(3))) void*)l, 16, 0, 0);
}

// ---------------- bert stage a: split beft into A2 = [hi | lo | hi], K=3072, 2048 rows ----------------
__global__ __launch_bounds__(256) void split_beft(const float* __restrict__ beft,
                                                  unsigned short* __restrict__ A2) {
    int l = blockIdx.x;
    int t = threadIdx.x;
    unsigned short* row = A2 + (size_t)l * 3072;
    for (int k = t; k < 1024; k += 256) {
        unsigned short hi = 0, lo = 0;
        if (l < L_RES) {
            float x = beft[(size_t)l * 1024 + k];
            hi = f2bf(x);
            lo = f2bf(x - bf2f(hi));
        }
        row[k] = hi;
        row[1024 + k] = lo;
        row[2048 + k] = hi;
    }
}

// ---------------- bert stage b: B2T[64][3072]: segs {hi,hi,lo} of Wb^T ----------------
__global__ __launch_bounds__(256) void b2t_build(const float* __restrict__ Wb,
                                                 unsigned short* __restrict__ B2T) {
    int idx = blockIdx.x * 256 + threadIdx.x;   // 64*3072 = 196608
    int n = idx / 3072, col = idx % 3072;
    int seg = col >> 10, k = col & 1023;
    unsigned short r = 0;
    if (n < DF) {
        float v = Wb[(size_t)k * DF + n];
        unsigned short hi = f2bf(v);
        r = (seg < 2) ? hi : f2bf(v - bf2f(hi));
    }
    B2T[idx] = r;
}

// ---------------- bert stage c: MFMA GEMM M=2048 N=64, K-split z=4 -> fp32 partials ----------------
__global__ __launch_bounds__(256) void bert_mfma(const unsigned short* __restrict__ A2,
                                                 const unsigned short* __restrict__ B2T,
                                                 float* __restrict__ bpart) {
    __shared__ unsigned short ldsA[128 * 64];
    __shared__ unsigned short ldsB[64 * 64];
    int t = threadIdx.x, w = t >> 6, lane = t & 63;
    int m0 = blockIdx.x * 128;
    int z = blockIdx.y;                       // 4 K-slices of 768
    long koff = (long)z * 768;
    int wr = w >> 1, wc = w & 1;
    int arow = lane & 15, kgrp = lane >> 4;

    const unsigned short* aS[4]; const unsigned short* bS[2];
    int aD[4], bD[2];
    #pragma unroll
    for (int j = 0; j < 4; ++j) {
        int s = j * 256 + t, r = s >> 3, c = s & 7;
        aS[j] = A2 + koff + (size_t)(m0 + r) * 3072 + c * 8;
        aD[j] = r * 64 + ((c ^ (r & 7)) * 8);
    }
    #pragma unroll
    for (int j = 0; j < 2; ++j) {
        int s = j * 256 + t, r = s >> 3, c = s & 7;
        bS[j] = B2T + koff + (size_t)r * 3072 + c * 8;
        bD[j] = r * 64 + ((c ^ (r & 7)) * 8);
    }
    f32x4 acc[4][2];
    #pragma unroll
    for (int mi = 0; mi < 4; ++mi)
        #pragma unroll
        for (int ni = 0; ni < 2; ++ni) acc[mi][ni] = (f32x4)(0.f);

    ushort8v va[4], vb[2];
    #pragma unroll
    for (int j = 0; j < 4; ++j) va[j] = *(const ushort8v*)(aS[j]);
    #pragma unroll
    for (int j = 0; j < 2; ++j) vb[j] = *(const ushort8v*)(bS[j]);

    for (int ks = 0; ks < 12; ++ks) {
        __syncthreads();
        #pragma unroll
        for (int j = 0; j < 4; ++j) *(ushort8v*)&ldsA[aD[j]] = va[j];
        #pragma unroll
        for (int j = 0; j < 2; ++j) *(ushort8v*)&ldsB[bD[j]] = vb[j];
        __syncthreads();
        if (ks + 1 < 12) {
            #pragma unroll
            for (int j = 0; j < 4; ++j) va[j] = *(const ushort8v*)(aS[j] + (ks + 1) * 64);
            #pragma unroll
            for (int j = 0; j < 2; ++j) vb[j] = *(const ushort8v*)(bS[j] + (ks + 1) * 64);
        }
        #pragma unroll
        for (int kk = 0; kk < 2; ++kk) {
            int chunk = kk * 4 + kgrp;
            bf16x8 af[4], bfr[2];
            #pragma unroll
            for (int mi = 0; mi < 4; ++mi) {
                int rl = wr * 64 + mi * 16 + arow;
                af[mi] = *(const bf16x8*)&ldsA[rl * 64 + ((chunk ^ (rl & 7)) * 8)];
            }
            #pragma unroll
            for (int ni = 0; ni < 2; ++ni) {
                int rl = wc * 32 + ni * 16 + arow;
                bfr[ni] = *(const bf16x8*)&ldsB[rl * 64 + ((chunk ^ (rl & 7)) * 8)];
            }
            #pragma unroll
            for (int mi = 0; mi < 4; ++mi)
                #pragma unroll
                for (int ni = 0; ni < 2; ++ni)
                    acc[mi][ni] = __builtin_amdgcn_mfma_f32_16x16x32_bf16(af[mi], bfr[ni], acc[mi][ni], 0, 0, 0);
        }
    }
    #pragma unroll
    for (int ni = 0; ni < 2; ++ni) {
        int n = wc * 32 + ni * 16 + arow;
        #pragma unroll
        for (int mi = 0; mi < 4; ++mi)
            #pragma unroll
            for (int r = 0; r < 4; ++r) {
                int m = m0 + wr * 64 + mi * 16 + kgrp * 4 + r;
                bpart[((size_t)z * 2048 + m) * 64 + n] = acc[mi][ni][r];
            }
    }
}

// ---------------- bert stage d: reduce 4 partials + bias -> f (L,54) ----------------
__global__ __launch_bounds__(64) void bert_reduce(const float* __restrict__ bpart,
                                                  const float* __restrict__ bb,
                                                  float* __restrict__ f) {
    int l = blockIdx.x, n = threadIdx.x;
    if (n < DF) {
        float s = bb[n];
        #pragma unroll
        for (int z = 0; z < 4; ++z) s += bpart[((size_t)z * 2048 + l) * 64 + n];
        f[(size_t)l * DF + n] = s;
    }
}

// ---------------- window gather + attn x2 + concat: 64-thread blocks (barriers elided) ----------------
__device__ __forceinline__ void attn_layer(const float (*in)[DF], float (*out)[DF],
                                           float (*s)[WIN][WIN],
                                           const float* __restrict__ g,
                                           const float* __restrict__ b,
                                           float* mm, float* vv, int t) {
    for (int idx = t; idx < 3 * WIN * WIN; idx += 64) {
        int h = idx / 49, r = idx % 49, q = r / WIN, k = r % WIN;
        float sum = 0.f;
        #pragma unroll
        for (int d = 0; d < 18; ++d) sum = fmaf(in[q][h * 18 + d], in[k][h * 18 + d], sum);
        s[h][q][k] = sum;
    }
    __syncthreads();
    for (int idx = t; idx < 3 * WIN; idx += 64) {
        int h = idx / WIN, q = idx % WIN;
        float mx = s[h][q][0];
        #pragma unroll
        for (int k = 1; k < WIN; ++k) mx = fmaxf(mx, s[h][q][k]);
        float e[WIN], sum = 0.f;
        #pragma unroll
        for (int k = 0; k < WIN; ++k) { e[k] = expf(s[h][q][k] - mx); sum += e[k]; }
        float inv = 1.f / sum;
        #pragma unroll
        for (int k = 0; k < WIN; ++k) s[h][q][k] = e[k] * inv;
    }
    __syncthreads();
    for (int idx = t; idx < WIN * DF; idx += 64) {
        int q = idx / DF, c = idx % DF, h = c / 18;
        float sum = 0.f;
        #pragma unroll
        for (int k = 0; k < WIN; ++k) sum = fmaf(s[h][q][k], in[k][c], sum);
        out[q][c] = sum;
    }
    __syncthreads();
    for (int q = t; q < WIN; q += 64) {
        float m = 0.f;
        for (int c = 0; c < DF; ++c) m += out[q][c];
        m *= (1.f / DF);
        float v = 0.f;
        for (int c = 0; c < DF; ++c) { float d0 = out[q][c] - m; v = fmaf(d0, d0, v); }
        v *= (1.f / DF);
        mm[q] = m; vv[q] = rsqrtf(v + 1e-5f);
    }
    __syncthreads();
    for (int idx = t; idx < WIN * DF; idx += 64) {
        int q = idx / DF, c = idx % DF;
        out[q][c] = (out[q][c] - mm[q]) * vv[q] * g[c] + b[c];
    }
    __syncthreads();
}

__global__ __launch_bounds__(64) void window_attn(const float* __restrict__ f,
                                                  const float* __restrict__ g1,
                                                  const float* __restrict__ b1,
                                                  const float* __restrict__ g2,
                                                  const float* __restrict__ b2,
                                                  float* __restrict__ cat) {
    int l = blockIdx.x;
    int t = threadIdx.x;
    __shared__ float w[WIN][DF], o1[WIN][DF], o2[WIN][DF];
    __shared__ float s[3][WIN][WIN];
    __shared__ float mm[WIN], vv[WIN];
    bool boundary = (l <= WIN) || (l + WIN >= L_RES);
    for (int idx = t; idx < WIN * DF; idx += 64) {
        int j = idx / DF, d = idx % DF;
        w[j][d] = boundary ? (j == 0 ? f[(size_t)l * DF + d] : 0.f)
                           : f[(size_t)(l - 4 + j) * DF + d];
    }
    __syncthreads();
    attn_layer(w, o1, s, g1, b1, mm, vv, t);
    attn_layer(o1, o2, s, g2, b2, mm, vv, t);
    for (int idx = t; idx < WIN * DF; idx += 64) {
        int j = idx / DF, d = idx % DF;
        cat[(size_t)l * 756 + j * 108 + d] = w[j][d];
        cat[(size_t)l * 756 + j * 108 + DF + d] = o2[j][d];
    }
}

// ---------------- transpose + f32->bf16: dst[n][m], rows m>=M zero-padded ----------------
__global__ __launch_bounds__(256) void transpose_to_bf16(const float* __restrict__ src,
                                                         unsigned short* __restrict__ dst,
                                                         int M, int N, int Mpad) {
    __shared__ float tile[32][33];
    int m0 = blockIdx.x * 32, n0 = blockIdx.y * 32;
    int c = threadIdx.x % 32, r0 = threadIdx.x / 32;
    #pragma unroll
    for (int rr = 0; rr < 4; ++rr) {
        int r = r0 + rr * 8, m = m0 + r;
        tile[r][c] = (m < M) ? src[(size_t)m * N + n0 + c] : 0.f;
    }
    __syncthreads();
    #pragma unroll
    for (int rr = 0; rr < 4; ++rr) {
        int r = r0 + rr * 8;
        dst[(size_t)(n0 + r) * Mpad + m0 + c] = f2bf(tile[c][r]);
    }
}

// ---------------- conv+pool -> Apool[nt*128][1024] bf16 ----------------
// grid = nt*4: b = bid>>2 (M-tile of 4 residues), ch0 = (bid&3)*8.
// wave = one residue (res = t>>6, dp = t&63<54); 8-channel wave-uniform loop ->
// scalar weight loads; per-(c,p) store = one contiguous 216B run per wave.
__global__ __launch_bounds__(256) void conv_pool(
        const float* __restrict__ cat,
        const float* __restrict__ c1w, const float* __restrict__ c1b,
        const float* __restrict__ pa_p,
        const float* __restrict__ c2w, const float* __restrict__ c2b,
        const float* __restrict__ c3w, const float* __restrict__ c3b,
        unsigned short* __restrict__ Ap, int lbase) {
    int bid = blockIdx.x;
    int b = bid >> 2;
    int ch0 = (bid & 3) * 8;
    int l0 = lbase + b * 4;
    int t = threadIdx.x;
    __shared__ float catl[4 * 756];
    for (int i = t; i < 3024; i += 256) catl[i] = cat[(size_t)l0 * 756 + i];
    __syncthreads();
    float pa = pa_p[0];
    unsigned short* base = Ap + (size_t)b * 128 * 1024;
    int res = t >> 6, dp = t & 63;
    if (dp < 54) {
        int d0 = dp * 2;
        const float* cr = catl + res * 756;
        float colA[WIN], colB[WIN];
        #pragma unroll
        for (int h = 0; h < WIN; ++h) {
            colA[h] = cr[h * 108 + d0];
            colB[h] = cr[h * 108 + d0 + 1];
        }
        for (int c = ch0; c < ch0 + 8; ++c) {             // wave-uniform channel loop
            unsigned short* Arow = base + (size_t)(res * 32 + c) * 1024;
            {   // branch 1: k=3, prelu, pool3 -> 5 outputs
                float w0 = c1w[c * 3], w1 = c1w[c * 3 + 1], w2 = c1w[c * 3 + 2];
                float bb = c1b[c];
                float vA[WIN], vB[WIN];
                #pragma unroll
                for (int h = 0; h < WIN; ++h) {
                    float sA = bb, sB = bb;
                    if (h >= 1) { sA = fmaf(w0, colA[h - 1], sA); sB = fmaf(w0, colB[h - 1], sB); }
                    sA = fmaf(w1, colA[h], sA); sB = fmaf(w1, colB[h], sB);
                    if (h <= 5) { sA = fmaf(w2, colA[h + 1], sA); sB = fmaf(w2, colB[h + 1], sB); }
                    vA[h] = sA >= 0.f ? sA : pa * sA;
                    vB[h] = sB >= 0.f ? sB : pa * sB;
                }
                #pragma unroll
                for (int p = 0; p < 5; ++p) {
                    unsigned int ua = f2bf(fmaxf(fmaxf(vA[p], vA[p + 1]), vA[p + 2]));
                    unsigned int ub = f2bf(fmaxf(fmaxf(vB[p], vB[p + 1]), vB[p + 2]));
                    *(unsigned int*)&Arow[p * 108 + d0] = ua | (ub << 16);
                }
            }
            {   // branch 2: k=5, relu, pool5 -> 3 outputs
                float wg[5], bb = c2b[c];
                #pragma unroll
                for (int x = 0; x < 5; ++x) wg[x] = c2w[c * 5 + x];
                float vA[WIN], vB[WIN];
                #pragma unroll
                for (int h = 0; h < WIN; ++h) {
                    float sA = bb, sB = bb;
                    #pragma unroll
                    for (int x = 0; x < 5; ++x) {
                        int hh = h + x - 2;
                        if (hh >= 0 && hh <= 6) {
                            sA = fmaf(wg[x], colA[hh], sA);
                            sB = fmaf(wg[x], colB[hh], sB);
                        }
                    }
                    vA[h] = fmaxf(sA, 0.f);
                    vB[h] = fmaxf(sB, 0.f);
                }
                #pragma unroll
                for (int p = 0; p < 3; ++p) {
                    float ma = vA[p], mb = vB[p];
                    #pragma unroll
                    for (int r = 1; r < 5; ++r) { ma = fmaxf(ma, vA[p + r]); mb = fmaxf(mb, vB[p + r]); }
                    unsigned int ua = f2bf(ma), ub = f2bf(mb);
                    *(unsigned int*)&Arow[540 + p * 108 + d0] = ua | (ub << 16);
                }
            }
            {   // branch 3: k=7, relu, pool7 -> 1 output
                float wg[7], bb = c3b[c];
                #pragma unroll
                for (int x = 0; x < 7; ++x) wg[x] = c3w[c * 7 + x];
                float ma = 0.f, mb = 0.f;
                #pragma unroll
                for (int h = 0; h < WIN; ++h) {
                    float sA = bb, sB = bb;
                    #pragma unroll
                    for (int x = 0; x < 7; ++x) {
                        int hh = h + x - 3;
                        if (hh >= 0 && hh <= 6) {
                            sA = fmaf(wg[x], colA[hh], sA);
                            sB = fmaf(wg[x], colB[hh], sB);
                        }
                    }
                    ma = fmaxf(ma, sA);
                    mb = fmaxf(mb, sB);
                }
                unsigned int ua = f2bf(fmaxf(ma, 0.f)), ub = f2bf(fmaxf(mb, 0.f));
                *(unsigned int*)&Arow[864 + d0] = ua | (ub << 16);
            }
        }
    }
    // zero K-pad cols 972..1023 for this block's 32 rows (26 u32 per row)
    for (int i = t; i < 832; i += 256) {
        int r = i / 26, q = i - r * 26;           // r in 0..31
        int res2 = r >> 3, c2 = ch0 + (r & 7);
        *(unsigned int*)&base[(size_t)(res2 * 32 + c2) * 1024 + 972 + q * 2] = 0u;
    }
}

// ---------------- 8-wave tiled MFMA GEMM, global_load_lds staging, C[128x256]/block ----------------
// LDS kept LINEAR; the XOR swizzle is applied to the per-lane GLOBAL source column (c^ra,
// an involution) so swizzled ds_read_b128 finds source[r][chunk] at col chunk^(r&7).
template<bool EPI_BF16, int ZBITS>
__global__ __launch_bounds__(512) void gemm_tile8(
        const unsigned short* __restrict__ A, long lda,
        const unsigned short* __restrict__ B, long ldb,
        int nk, const float* __restrict__ bias,
        unsigned short* __restrict__ outB, float* __restrict__ outF,
        long outRowBase) {
    __shared__ unsigned short ldsA[128 * 64];
    __shared__ unsigned short ldsB[256 * 64];
    int t = threadIdx.x, w = t >> 6, lane = t & 63;
    int bid = blockIdx.x;
    int z = bid & ((1 << ZBITS) - 1);
    long m0 = (long)(bid >> ZBITS) * 128;
    long koff = (long)z * (long)nk * 64;
    A += koff; B += koff;
    int wr = w >> 2, wc = w & 3;                 // 2 x 4 wave grid, 64x64 each
    int arow = lane & 15, kgrp = lane >> 4;
    int ra = lane >> 3, cc = lane & 7;
    int csw = (cc ^ ra) * 8;                     // pre-swizzled source column

    const unsigned short* gA[2]; const unsigned short* gB[4];
    unsigned short* dA[2]; unsigned short* dB[4];
    #pragma unroll
    for (int j = 0; j < 2; ++j) {
        int rbase = j * 64 + w * 8;
        gA[j] = A + (size_t)(m0 + rbase + ra) * lda + csw;
        dA[j] = &ldsA[rbase * 64];
    }
    #pragma unroll
    for (int j = 0; j < 4; ++j) {
        int rbase = j * 64 + w * 8;
        gB[j] = B + (size_t)(rbase + ra) * ldb + csw;
        dB[j] = &ldsB[rbase * 64];
    }
    f32x4 acc[4][4];
    #pragma unroll
    for (int mi = 0; mi < 4; ++mi)
        #pragma unroll
        for (int ni = 0; ni < 4; ++ni) acc[mi][ni] = (f32x4)(0.f);

    for (int ks = 0; ks < nk; ++ks) {
        #pragma unroll
        for (int j = 0; j < 2; ++j) gload16(gA[j] + ks * 64, dA[j]);
        #pragma unroll
        for (int j = 0; j < 4; ++j) gload16(gB[j] + ks * 64, dB[j]);
        __syncthreads();                          // drains vmcnt -> LDS tile ready
        #pragma unroll
        for (int kk = 0; kk < 2; ++kk) {
            int chunk = kk * 4 + kgrp;
            bf16x8 af[4], bfr[4];
            #pragma unroll
            for (int mi = 0; mi < 4; ++mi) {
                int rl = wr * 64 + mi * 16 + arow;
                af[mi] = *(const bf16x8*)&ldsA[rl * 64 + ((chunk ^ (rl & 7)) * 8)];
            }
            #pragma unroll
            for (int ni = 0; ni < 4; ++ni) {
                int rl = wc * 64 + ni * 16 + arow;
                bfr[ni] = *(const bf16x8*)&ldsB[rl * 64 + ((chunk ^ (rl & 7)) * 8)];
            }
            #pragma unroll
            for (int mi = 0; mi < 4; ++mi)
                #pragma unroll
                for (int ni = 0; ni < 4; ++ni)
                    acc[mi][ni] = __builtin_amdgcn_mfma_f32_16x16x32_bf16(af[mi], bfr[ni], acc[mi][ni], 0, 0, 0);
        }
        __syncthreads();                          // all reads done before next stage
    }
    #pragma unroll
    for (int ni = 0; ni < 4; ++ni) {
        int n = wc * 64 + ni * 16 + arow;
        float bv = EPI_BF16 ? bias[n] : 0.f;
        #pragma unroll
        for (int mi = 0; mi < 4; ++mi)
            #pragma unroll
            for (int r = 0; r < 4; ++r) {
                long m = m0 + wr * 64 + mi * 16 + kgrp * 4 + r;
                if (EPI_BF16)
                    outB[(outRowBase + m) * 256 + n] = f2bf(acc[mi][ni][r] + bv);
                else
                    outF[((long)z * 2048 + m) * 256 + n] = acc[mi][ni][r];
            }
    }
}

// ---------------- reduce partials (16 K-slices) + bias + leaky ----------------
__global__ __launch_bounds__(256) void reduce2(const float* __restrict__ part,
                                               const float* __restrict__ b2v,
                                               float* __restrict__ out) {
    int l = blockIdx.x, n = threadIdx.x;
    float sum = b2v[n];
    #pragma unroll
    for (int s = 0; s < 16; ++s) sum += part[((size_t)s * 2048 + l) * 256 + n];
    out[(size_t)l * 256 + n] = sum >= 0.f ? sum : 0.01f * sum;
}

extern "C" void kernel_launch(void* const* d_in, const int* in_sizes, int n_in,
                              void* d_out, int out_size, void* d_ws, size_t ws_size,
                              hipStream_t stream) {
    const float* beft = (const float*)d_in[0];
    const float* Wb  = (const float*)d_in[4];
    const float* bb  = (const float*)d_in[5];
    const float* g1  = (const float*)d_in[6];
    const float* b1  = (const float*)d_in[7];
    const float* g2  = (const float*)d_in[8];
    const float* b2  = (const float*)d_in[9];
    const float* c1w = (const float*)d_in[10];
    const float* c1b = (const float*)d_in[11];
    const float* pa  = (const float*)d_in[12];
    const float* c2w = (const float*)d_in[13];
    const float* c2b = (const float*)d_in[14];
    const float* c3w = (const float*)d_in[15];
    const float* c3b = (const float*)d_in[16];
    const float* W1  = (const float*)d_in[17];
    const float* b1v = (const float*)d_in[18];
    const float* W2  = (const float*)d_in[19];
    const float* b2v = (const float*)d_in[20];
    float* out = (float*)d_out;
    char* ws = (char*)d_ws;

    // layout (overlays are temporally disjoint):
    float*          f    = (float*)(ws + 0);                   // 432,000 B [dead after attn]
    float*          cat  = (float*)(ws + 524288);              // 6,048,000 B [dead after conv]
    unsigned short* W1T  = (unsigned short*)(ws + 8388608);    // 524,288 B
    unsigned short* W2T  = (unsigned short*)(ws + 8912896);    // 4,194,304 B
    unsigned short* y1   = (unsigned short*)(ws + 13107200);   // 33,554,432 B
    unsigned short* A2   = (unsigned short*)(ws + 13107200);   // 12,582,912 B [bert phase, overlays y1]
    unsigned short* B2T  = (unsigned short*)(ws + 25690112);   // 393,216 B    [bert phase, within y1]
    float*          bpart= (float*)(ws + 46661632);            // 2,097,152 B  [bert phase]
    unsigned short* Ap   = (unsigned short*)(ws + 46661632);   // Apool chunk  [conv/gemm1 phase]
    float*          part = (float*)(ws + 46661632);            // 33,554,432 B [gemm2 phase]

    long avail = (long)ws_size - 46661632L;
    long tpc = avail / (128L * 1024L * 2L);
    if (tpc < 1) tpc = 1;
    if (tpc > 500) tpc = 500;

    split_beft<<<2048, 256, 0, stream>>>(beft, A2);
    b2t_build<<<768, 256, 0, stream>>>(Wb, B2T);
    bert_mfma<<<dim3(16, 4), 256, 0, stream>>>(A2, B2T, bpart);
    bert_reduce<<<L_RES, 64, 0, stream>>>(bpart, bb, f);
    window_attn<<<L_RES, 64, 0, stream>>>(f, g1, b1, g2, b2, cat);
    transpose_to_bf16<<<dim3(32, 8), 256, 0, stream>>>(W1, W1T, 972, 256, 1024);
    transpose_to_bf16<<<dim3(256, 8), 256, 0, stream>>>(W2, W2T, 8192, 256, 8192);
    // y1 pad rows 2000..2047 NOT zeroed: gemm2 garbage from those A-rows lands only
    // in part rows >= 2000, which reduce2 never reads.

    for (long t0 = 0; t0 < 500; t0 += tpc) {
        long nt = (500 - t0 < tpc) ? (500 - t0) : tpc;
        conv_pool<<<(int)(nt * 4), 256, 0, stream>>>(cat, c1w, c1b, pa, c2w, c2b,
                                                     c3w, c3b, Ap, (int)(t0 * 4));
        gemm_tile8<true, 0><<<(int)nt, 512, 0, stream>>>(
            Ap, 1024, W1T, 1024, 16, b1v, y1, nullptr, t0 * 128);
    }
    gemm_tile8<false, 4><<<256, 512, 0, stream>>>(
        y1, 8192, W2T, 8192, 8, nullptr, nullptr, part, 0);
    reduce2<<<L_RES, 256, 0, stream>>>(part, b2v, out);
}

// Round 13
// 146.005 us; speedup vs baseline: 1.2747x; 1.0446x over previous
//
#include <hip/hip_runtime.h>

#define L_RES 2000
#define DF 54
#define WIN 7

typedef short bf16x8 __attribute__((ext_vector_type(8)));
typedef float f32x4 __attribute__((ext_vector_type(4)));
typedef unsigned short ushort8v __attribute__((ext_vector_type(8)));

__device__ __forceinline__ unsigned short f2bf(float f) {
    unsigned int u = __float_as_uint(f);
    unsigned int r = (u + 0x7FFFu + ((u >> 16) & 1u)) >> 16;
    return (unsigned short)r;
}
__device__ __forceinline__ float bf2f(unsigned short h) {
    return __uint_as_float(((unsigned int)h) << 16);
}
// async global->LDS, 16B per lane; LDS dest = wave-uniform base + lane*16
__device__ __forceinline__ void gload16(const unsigned short* g, unsigned short* l) {
    __builtin_amdgcn_global_load_lds(
        (const __attribute__((address_space(1))) void*)g,
        (__attribute__((address_space(3))) void*)l, 16, 0, 0);
}

// ---------------- bert stage a: split beft into A2 = [hi | lo | hi], K=3072, 2048 rows ----------------
__global__ __launch_bounds__(256) void split_beft(const float* __restrict__ beft,
                                                  unsigned short* __restrict__ A2) {
    int l = blockIdx.x;
    int t = threadIdx.x;
    unsigned short* row = A2 + (size_t)l * 3072;
    for (int k = t; k < 1024; k += 256) {
        unsigned short hi = 0, lo = 0;
        if (l < L_RES) {
            float x = beft[(size_t)l * 1024 + k];
            hi = f2bf(x);
            lo = f2bf(x - bf2f(hi));
        }
        row[k] = hi;
        row[1024 + k] = lo;
        row[2048 + k] = hi;
    }
}

// ---------------- bert stage b: B2T[64][3072]: segs {hi,hi,lo} of Wb^T ----------------
__global__ __launch_bounds__(256) void b2t_build(const float* __restrict__ Wb,
                                                 unsigned short* __restrict__ B2T) {
    int idx = blockIdx.x * 256 + threadIdx.x;   // 64*3072 = 196608
    int n = idx / 3072, col = idx % 3072;
    int seg = col >> 10, k = col & 1023;
    unsigned short r = 0;
    if (n < DF) {
        float v = Wb[(size_t)k * DF + n];
        unsigned short hi = f2bf(v);
        r = (seg < 2) ? hi : f2bf(v - bf2f(hi));
    }
    B2T[idx] = r;
}

// ---------------- bert stage c: MFMA GEMM M=2048 N=64, K-split z=4 -> fp32 partials ----------------
__global__ __launch_bounds__(256) void bert_mfma(const unsigned short* __restrict__ A2,
                                                 const unsigned short* __restrict__ B2T,
                                                 float* __restrict__ bpart) {
    __shared__ unsigned short ldsA[128 * 64];
    __shared__ unsigned short ldsB[64 * 64];
    int t = threadIdx.x, w = t >> 6, lane = t & 63;
    int m0 = blockIdx.x * 128;
    int z = blockIdx.y;                       // 4 K-slices of 768
    long koff = (long)z * 768;
    int wr = w >> 1, wc = w & 1;
    int arow = lane & 15, kgrp = lane >> 4;

    const unsigned short* aS[4]; const unsigned short* bS[2];
    int aD[4], bD[2];
    #pragma unroll
    for (int j = 0; j < 4; ++j) {
        int s = j * 256 + t, r = s >> 3, c = s & 7;
        aS[j] = A2 + koff + (size_t)(m0 + r) * 3072 + c * 8;
        aD[j] = r * 64 + ((c ^ (r & 7)) * 8);
    }
    #pragma unroll
    for (int j = 0; j < 2; ++j) {
        int s = j * 256 + t, r = s >> 3, c = s & 7;
        bS[j] = B2T + koff + (size_t)r * 3072 + c * 8;
        bD[j] = r * 64 + ((c ^ (r & 7)) * 8);
    }
    f32x4 acc[4][2];
    #pragma unroll
    for (int mi = 0; mi < 4; ++mi)
        #pragma unroll
        for (int ni = 0; ni < 2; ++ni) acc[mi][ni] = (f32x4)(0.f);

    ushort8v va[4], vb[2];
    #pragma unroll
    for (int j = 0; j < 4; ++j) va[j] = *(const ushort8v*)(aS[j]);
    #pragma unroll
    for (int j = 0; j < 2; ++j) vb[j] = *(const ushort8v*)(bS[j]);

    for (int ks = 0; ks < 12; ++ks) {
        __syncthreads();
        #pragma unroll
        for (int j = 0; j < 4; ++j) *(ushort8v*)&ldsA[aD[j]] = va[j];
        #pragma unroll
        for (int j = 0; j < 2; ++j) *(ushort8v*)&ldsB[bD[j]] = vb[j];
        __syncthreads();
        if (ks + 1 < 12) {
            #pragma unroll
            for (int j = 0; j < 4; ++j) va[j] = *(const ushort8v*)(aS[j] + (ks + 1) * 64);
            #pragma unroll
            for (int j = 0; j < 2; ++j) vb[j] = *(const ushort8v*)(bS[j] + (ks + 1) * 64);
        }
        #pragma unroll
        for (int kk = 0; kk < 2; ++kk) {
            int chunk = kk * 4 + kgrp;
            bf16x8 af[4], bfr[2];
            #pragma unroll
            for (int mi = 0; mi < 4; ++mi) {
                int rl = wr * 64 + mi * 16 + arow;
                af[mi] = *(const bf16x8*)&ldsA[rl * 64 + ((chunk ^ (rl & 7)) * 8)];
            }
            #pragma unroll
            for (int ni = 0; ni < 2; ++ni) {
                int rl = wc * 32 + ni * 16 + arow;
                bfr[ni] = *(const bf16x8*)&ldsB[rl * 64 + ((chunk ^ (rl & 7)) * 8)];
            }
            #pragma unroll
            for (int mi = 0; mi < 4; ++mi)
                #pragma unroll
                for (int ni = 0; ni < 2; ++ni)
                    acc[mi][ni] = __builtin_amdgcn_mfma_f32_16x16x32_bf16(af[mi], bfr[ni], acc[mi][ni], 0, 0, 0);
        }
    }
    #pragma unroll
    for (int ni = 0; ni < 2; ++ni) {
        int n = wc * 32 + ni * 16 + arow;
        #pragma unroll
        for (int mi = 0; mi < 4; ++mi)
            #pragma unroll
            for (int r = 0; r < 4; ++r) {
                int m = m0 + wr * 64 + mi * 16 + kgrp * 4 + r;
                bpart[((size_t)z * 2048 + m) * 64 + n] = acc[mi][ni][r];
            }
    }
}

// ---------------- bert stage d: reduce 4 partials + bias -> f (L,54) ----------------
__global__ __launch_bounds__(64) void bert_reduce(const float* __restrict__ bpart,
                                                  const float* __restrict__ bb,
                                                  float* __restrict__ f) {
    int l = blockIdx.x, n = threadIdx.x;
    if (n < DF) {
        float s = bb[n];
        #pragma unroll
        for (int z = 0; z < 4; ++z) s += bpart[((size_t)z * 2048 + l) * 64 + n];
        f[(size_t)l * DF + n] = s;
    }
}

// ---------------- window gather + attn x2 + concat: 64-thread blocks (barriers elided) ----------------
__device__ __forceinline__ void attn_layer(const float (*in)[DF], float (*out)[DF],
                                           float (*s)[WIN][WIN],
                                           const float* __restrict__ g,
                                           const float* __restrict__ b,
                                           float* mm, float* vv, int t) {
    for (int idx = t; idx < 3 * WIN * WIN; idx += 64) {
        int h = idx / 49, r = idx % 49, q = r / WIN, k = r % WIN;
        float sum = 0.f;
        #pragma unroll
        for (int d = 0; d < 18; ++d) sum = fmaf(in[q][h * 18 + d], in[k][h * 18 + d], sum);
        s[h][q][k] = sum;
    }
    __syncthreads();
    for (int idx = t; idx < 3 * WIN; idx += 64) {
        int h = idx / WIN, q = idx % WIN;
        float mx = s[h][q][0];
        #pragma unroll
        for (int k = 1; k < WIN; ++k) mx = fmaxf(mx, s[h][q][k]);
        float e[WIN], sum = 0.f;
        #pragma unroll
        for (int k = 0; k < WIN; ++k) { e[k] = expf(s[h][q][k] - mx); sum += e[k]; }
        float inv = 1.f / sum;
        #pragma unroll
        for (int k = 0; k < WIN; ++k) s[h][q][k] = e[k] * inv;
    }
    __syncthreads();
    for (int idx = t; idx < WIN * DF; idx += 64) {
        int q = idx / DF, c = idx % DF, h = c / 18;
        float sum = 0.f;
        #pragma unroll
        for (int k = 0; k < WIN; ++k) sum = fmaf(s[h][q][k], in[k][c], sum);
        out[q][c] = sum;
    }
    __syncthreads();
    for (int q = t; q < WIN; q += 64) {
        float m = 0.f;
        for (int c = 0; c < DF; ++c) m += out[q][c];
        m *= (1.f / DF);
        float v = 0.f;
        for (int c = 0; c < DF; ++c) { float d0 = out[q][c] - m; v = fmaf(d0, d0, v); }
        v *= (1.f / DF);
        mm[q] = m; vv[q] = rsqrtf(v + 1e-5f);
    }
    __syncthreads();
    for (int idx = t; idx < WIN * DF; idx += 64) {
        int q = idx / DF, c = idx % DF;
        out[q][c] = (out[q][c] - mm[q]) * vv[q] * g[c] + b[c];
    }
    __syncthreads();
}

__global__ __launch_bounds__(64) void window_attn(const float* __restrict__ f,
                                                  const float* __restrict__ g1,
                                                  const float* __restrict__ b1,
                                                  const float* __restrict__ g2,
                                                  const float* __restrict__ b2,
                                                  float* __restrict__ cat) {
    int l = blockIdx.x;
    int t = threadIdx.x;
    __shared__ float w[WIN][DF], o1[WIN][DF], o2[WIN][DF];
    __shared__ float s[3][WIN][WIN];
    __shared__ float mm[WIN], vv[WIN];
    bool boundary = (l <= WIN) || (l + WIN >= L_RES);
    for (int idx = t; idx < WIN * DF; idx += 64) {
        int j = idx / DF, d = idx % DF;
        w[j][d] = boundary ? (j == 0 ? f[(size_t)l * DF + d] : 0.f)
                           : f[(size_t)(l - 4 + j) * DF + d];
    }
    __syncthreads();
    attn_layer(w, o1, s, g1, b1, mm, vv, t);
    attn_layer(o1, o2, s, g2, b2, mm, vv, t);
    for (int idx = t; idx < WIN * DF; idx += 64) {
        int j = idx / DF, d = idx % DF;
        cat[(size_t)l * 756 + j * 108 + d] = w[j][d];
        cat[(size_t)l * 756 + j * 108 + DF + d] = o2[j][d];
    }
}

// ---------------- transpose + f32->bf16: dst[n][m], rows m>=M zero-padded (W2T) ----------------
__global__ __launch_bounds__(256) void transpose_to_bf16(const float* __restrict__ src,
                                                         unsigned short* __restrict__ dst,
                                                         int M, int N, int Mpad) {
    __shared__ float tile[32][33];
    int m0 = blockIdx.x * 32, n0 = blockIdx.y * 32;
    int c = threadIdx.x % 32, r0 = threadIdx.x / 32;
    #pragma unroll
    for (int rr = 0; rr < 4; ++rr) {
        int r = r0 + rr * 8, m = m0 + r;
        tile[r][c] = (m < M) ? src[(size_t)m * N + n0 + c] : 0.f;
    }
    __syncthreads();
    #pragma unroll
    for (int rr = 0; rr < 4; ++rr) {
        int r = r0 + rr * 8;
        dst[(size_t)(n0 + r) * Mpad + m0 + c] = f2bf(tile[c][r]);
    }
}

// ---------------- W1Tp: pack W1 into MFMA b-frag order ----------------
// P[((nb*32 + ks*2 + kk)*64 + lane)*8 + e] = bf16(W1[k][n]),
//   n = nb*16 + (lane&15), k = ks*64 + kk*32 + (lane>>4)*8 + e (0 if k>=972)
__global__ __launch_bounds__(256) void w1tp_build(const float* __restrict__ W1,
                                                  unsigned short* __restrict__ P) {
    int idx = blockIdx.x * 256 + threadIdx.x;   // 262144
    int e = idx & 7, l = (idx >> 3) & 63, g = (idx >> 9) & 31, nb = idx >> 14;
    int ks = g >> 1, kk = g & 1;
    int n = nb * 16 + (l & 15);
    int k = ks * 64 + kk * 32 + (l >> 4) * 8 + e;
    P[idx] = (k < 972) ? f2bf(W1[(size_t)k * 256 + n]) : (unsigned short)0;
}

// ---------------- conv+pool -> Apool[nt*128][1024] bf16 ----------------
__global__ __launch_bounds__(256) void conv_pool(
        const float* __restrict__ cat,
        const float* __restrict__ c1w, const float* __restrict__ c1b,
        const float* __restrict__ pa_p,
        const float* __restrict__ c2w, const float* __restrict__ c2b,
        const float* __restrict__ c3w, const float* __restrict__ c3b,
        unsigned short* __restrict__ Ap, int lbase) {
    int bid = blockIdx.x;
    int b = bid >> 2;
    int ch0 = (bid & 3) * 8;
    int l0 = lbase + b * 4;
    int t = threadIdx.x;
    __shared__ float catl[4 * 756];
    for (int i = t; i < 3024; i += 256) catl[i] = cat[(size_t)l0 * 756 + i];
    __syncthreads();
    float pa = pa_p[0];
    unsigned short* base = Ap + (size_t)b * 128 * 1024;
    int res = t >> 6, dp = t & 63;
    if (dp < 54) {
        int d0 = dp * 2;
        const float* cr = catl + res * 756;
        float colA[WIN], colB[WIN];
        #pragma unroll
        for (int h = 0; h < WIN; ++h) {
            colA[h] = cr[h * 108 + d0];
            colB[h] = cr[h * 108 + d0 + 1];
        }
        for (int c = ch0; c < ch0 + 8; ++c) {             // wave-uniform channel loop
            unsigned short* Arow = base + (size_t)(res * 32 + c) * 1024;
            {   // branch 1: k=3, prelu, pool3 -> 5 outputs
                float w0 = c1w[c * 3], w1 = c1w[c * 3 + 1], w2 = c1w[c * 3 + 2];
                float bb = c1b[c];
                float vA[WIN], vB[WIN];
                #pragma unroll
                for (int h = 0; h < WIN; ++h) {
                    float sA = bb, sB = bb;
                    if (h >= 1) { sA = fmaf(w0, colA[h - 1], sA); sB = fmaf(w0, colB[h - 1], sB); }
                    sA = fmaf(w1, colA[h], sA); sB = fmaf(w1, colB[h], sB);
                    if (h <= 5) { sA = fmaf(w2, colA[h + 1], sA); sB = fmaf(w2, colB[h + 1], sB); }
                    vA[h] = sA >= 0.f ? sA : pa * sA;
                    vB[h] = sB >= 0.f ? sB : pa * sB;
                }
                #pragma unroll
                for (int p = 0; p < 5; ++p) {
                    unsigned int ua = f2bf(fmaxf(fmaxf(vA[p], vA[p + 1]), vA[p + 2]));
                    unsigned int ub = f2bf(fmaxf(fmaxf(vB[p], vB[p + 1]), vB[p + 2]));
                    *(unsigned int*)&Arow[p * 108 + d0] = ua | (ub << 16);
                }
            }
            {   // branch 2: k=5, relu, pool5 -> 3 outputs
                float wg[5], bb = c2b[c];
                #pragma unroll
                for (int x = 0; x < 5; ++x) wg[x] = c2w[c * 5 + x];
                float vA[WIN], vB[WIN];
                #pragma unroll
                for (int h = 0; h < WIN; ++h) {
                    float sA = bb, sB = bb;
                    #pragma unroll
                    for (int x = 0; x < 5; ++x) {
                        int hh = h + x - 2;
                        if (hh >= 0 && hh <= 6) {
                            sA = fmaf(wg[x], colA[hh], sA);
                            sB = fmaf(wg[x], colB[hh], sB);
                        }
                    }
                    vA[h] = fmaxf(sA, 0.f);
                    vB[h] = fmaxf(sB, 0.f);
                }
                #pragma unroll
                for (int p = 0; p < 3; ++p) {
                    float ma = vA[p], mb = vB[p];
                    #pragma unroll
                    for (int r = 1; r < 5; ++r) { ma = fmaxf(ma, vA[p + r]); mb = fmaxf(mb, vB[p + r]); }
                    unsigned int ua = f2bf(ma), ub = f2bf(mb);
                    *(unsigned int*)&Arow[540 + p * 108 + d0] = ua | (ub << 16);
                }
            }
            {   // branch 3: k=7, relu, pool7 -> 1 output
                float wg[7], bb = c3b[c];
                #pragma unroll
                for (int x = 0; x < 7; ++x) wg[x] = c3w[c * 7 + x];
                float ma = 0.f, mb = 0.f;
                #pragma unroll
                for (int h = 0; h < WIN; ++h) {
                    float sA = bb, sB = bb;
                    #pragma unroll
                    for (int x = 0; x < 7; ++x) {
                        int hh = h + x - 3;
                        if (hh >= 0 && hh <= 6) {
                            sA = fmaf(wg[x], colA[hh], sA);
                            sB = fmaf(wg[x], colB[hh], sB);
                        }
                    }
                    ma = fmaxf(ma, sA);
                    mb = fmaxf(mb, sB);
                }
                unsigned int ua = f2bf(fmaxf(ma, 0.f)), ub = f2bf(fmaxf(mb, 0.f));
                *(unsigned int*)&Arow[864 + d0] = ua | (ub << 16);
            }
        }
    }
    // zero K-pad cols 972..1023 for this block's 32 rows (26 u32 per row)
    for (int i = t; i < 832; i += 256) {
        int r = i / 26, q = i - r * 26;           // r in 0..31
        int res2 = r >> 3, c2 = ch0 + (r & 7);
        *(unsigned int*)&base[(size_t)(res2 * 32 + c2) * 1024 + 972 + q * 2] = 0u;
    }
}

// ---------------- GEMM1 v3: 2-phase dbuf A (gload_lds) + packed-fragment B direct ----------------
// 256 thr, 4 waves (1M x 4N), C[128x256]/block, K=1024 (16 K-steps of 64).
// A LDS dbuf 2x128x64 (32 KB), prefetch tile ks+1 issued before compute of ks; single
// barrier/iter (its vmcnt(0) drains the stage). B via W1Tp: 1KB contiguous per wave-frag.
__global__ __launch_bounds__(256, 2) void gemm1k(
        const unsigned short* __restrict__ A,
        const unsigned short* __restrict__ P,
        const float* __restrict__ b1v,
        unsigned short* __restrict__ y1, long outRowBase) {
    __shared__ unsigned short ldsA[2][128 * 64];
    int t = threadIdx.x, w = t >> 6, lane = t & 63;
    long m0 = (long)blockIdx.x * 128;
    int arow = lane & 15, kgrp = lane >> 4;
    int ra = lane >> 3, cc = lane & 7;
    int csw = (cc ^ ra) * 8;                     // pre-swizzled source column

    const unsigned short* gA[4]; int rb[4];
    #pragma unroll
    for (int j = 0; j < 4; ++j) {
        int rbase = j * 32 + w * 8;
        gA[j] = A + (size_t)(m0 + rbase + ra) * 1024 + csw;
        rb[j] = rbase * 64;
    }
    f32x4 acc[8][4];
    #pragma unroll
    for (int mi = 0; mi < 8; ++mi)
        #pragma unroll
        for (int ni = 0; ni < 4; ++ni) acc[mi][ni] = (f32x4)(0.f);

    // prologue: stage tile 0
    #pragma unroll
    for (int j = 0; j < 4; ++j) gload16(gA[j], &ldsA[0][rb[j]]);
    __syncthreads();

    for (int ks = 0; ks < 16; ++ks) {
        int cur = ks & 1;
        // b-frags for both kk first (so their vmcnt waits don't drain the stage)
        bf16x8 bfr[2][4];
        #pragma unroll
        for (int kk = 0; kk < 2; ++kk)
            #pragma unroll
            for (int ni = 0; ni < 4; ++ni)
                bfr[kk][ni] = *(const bf16x8*)&P[(((size_t)(w * 4 + ni) * 32 + ks * 2 + kk) * 64 + lane) * 8];
        // issue async stage of tile ks+1 into the other buffer
        if (ks + 1 < 16) {
            #pragma unroll
            for (int j = 0; j < 4; ++j) gload16(gA[j] + (ks + 1) * 64, &ldsA[cur ^ 1][rb[j]]);
        }
        #pragma unroll
        for (int kk = 0; kk < 2; ++kk) {
            int chunk = kk * 4 + kgrp;
            bf16x8 af[8];
            #pragma unroll
            for (int mi = 0; mi < 8; ++mi) {
                int rl = mi * 16 + arow;
                af[mi] = *(const bf16x8*)&ldsA[cur][rl * 64 + ((chunk ^ (rl & 7)) * 8)];
            }
            #pragma unroll
            for (int mi = 0; mi < 8; ++mi)
                #pragma unroll
                for (int ni = 0; ni < 4; ++ni)
                    acc[mi][ni] = __builtin_amdgcn_mfma_f32_16x16x32_bf16(af[mi], bfr[kk][ni], acc[mi][ni], 0, 0, 0);
        }
        __syncthreads();     // drains stage of ks+1; syncs reads-done on ldsA[cur]
    }
    // epilogue: bias + bf16 + direct store
    #pragma unroll
    for (int ni = 0; ni < 4; ++ni) {
        int n = w * 64 + ni * 16 + arow;
        float bv = b1v[n];
        #pragma unroll
        for (int mi = 0; mi < 8; ++mi)
            #pragma unroll
            for (int r = 0; r < 4; ++r) {
                long row = m0 + mi * 16 + kgrp * 4 + r;
                y1[(outRowBase + row) * 256 + n] = f2bf(acc[mi][ni][r] + bv);
            }
    }
}

// ---------------- 8-wave tiled MFMA GEMM (GEMM2), global_load_lds staging ----------------
template<bool EPI_BF16, int ZBITS>
__global__ __launch_bounds__(512) void gemm_tile8(
        const unsigned short* __restrict__ A, long lda,
        const unsigned short* __restrict__ B, long ldb,
        int nk, const float* __restrict__ bias,
        unsigned short* __restrict__ outB, float* __restrict__ outF,
        long outRowBase) {
    __shared__ unsigned short ldsA[128 * 64];
    __shared__ unsigned short ldsB[256 * 64];
    int t = threadIdx.x, w = t >> 6, lane = t & 63;
    int bid = blockIdx.x;
    int z = bid & ((1 << ZBITS) - 1);
    long m0 = (long)(bid >> ZBITS) * 128;
    long koff = (long)z * (long)nk * 64;
    A += koff; B += koff;
    int wr = w >> 2, wc = w & 3;
    int arow = lane & 15, kgrp = lane >> 4;
    int ra = lane >> 3, cc = lane & 7;
    int csw = (cc ^ ra) * 8;

    const unsigned short* gA[2]; const unsigned short* gB[4];
    unsigned short* dA[2]; unsigned short* dB[4];
    #pragma unroll
    for (int j = 0; j < 2; ++j) {
        int rbase = j * 64 + w * 8;
        gA[j] = A + (size_t)(m0 + rbase + ra) * lda + csw;
        dA[j] = &ldsA[rbase * 64];
    }
    #pragma unroll
    for (int j = 0; j < 4; ++j) {
        int rbase = j * 64 + w * 8;
        gB[j] = B + (size_t)(rbase + ra) * ldb + csw;
        dB[j] = &ldsB[rbase * 64];
    }
    f32x4 acc[4][4];
    #pragma unroll
    for (int mi = 0; mi < 4; ++mi)
        #pragma unroll
        for (int ni = 0; ni < 4; ++ni) acc[mi][ni] = (f32x4)(0.f);

    for (int ks = 0; ks < nk; ++ks) {
        #pragma unroll
        for (int j = 0; j < 2; ++j) gload16(gA[j] + ks * 64, dA[j]);
        #pragma unroll
        for (int j = 0; j < 4; ++j) gload16(gB[j] + ks * 64, dB[j]);
        __syncthreads();
        #pragma unroll
        for (int kk = 0; kk < 2; ++kk) {
            int chunk = kk * 4 + kgrp;
            bf16x8 af[4], bfr[4];
            #pragma unroll
            for (int mi = 0; mi < 4; ++mi) {
                int rl = wr * 64 + mi * 16 + arow;
                af[mi] = *(const bf16x8*)&ldsA[rl * 64 + ((chunk ^ (rl & 7)) * 8)];
            }
            #pragma unroll
            for (int ni = 0; ni < 4; ++ni) {
                int rl = wc * 64 + ni * 16 + arow;
                bfr[ni] = *(const bf16x8*)&ldsB[rl * 64 + ((chunk ^ (rl & 7)) * 8)];
            }
            #pragma unroll
            for (int mi = 0; mi < 4; ++mi)
                #pragma unroll
                for (int ni = 0; ni < 4; ++ni)
                    acc[mi][ni] = __builtin_amdgcn_mfma_f32_16x16x32_bf16(af[mi], bfr[ni], acc[mi][ni], 0, 0, 0);
        }
        __syncthreads();
    }
    #pragma unroll
    for (int ni = 0; ni < 4; ++ni) {
        int n = wc * 64 + ni * 16 + arow;
        float bv = EPI_BF16 ? bias[n] : 0.f;
        #pragma unroll
        for (int mi = 0; mi < 4; ++mi)
            #pragma unroll
            for (int r = 0; r < 4; ++r) {
                long m = m0 + wr * 64 + mi * 16 + kgrp * 4 + r;
                if (EPI_BF16)
                    outB[(outRowBase + m) * 256 + n] = f2bf(acc[mi][ni][r] + bv);
                else
                    outF[((long)z * 2048 + m) * 256 + n] = acc[mi][ni][r];
            }
    }
}

// ---------------- reduce partials (16 K-slices) + bias + leaky ----------------
__global__ __launch_bounds__(256) void reduce2(const float* __restrict__ part,
                                               const float* __restrict__ b2v,
                                               float* __restrict__ out) {
    int l = blockIdx.x, n = threadIdx.x;
    float sum = b2v[n];
    #pragma unroll
    for (int s = 0; s < 16; ++s) sum += part[((size_t)s * 2048 + l) * 256 + n];
    out[(size_t)l * 256 + n] = sum >= 0.f ? sum : 0.01f * sum;
}

extern "C" void kernel_launch(void* const* d_in, const int* in_sizes, int n_in,
                              void* d_out, int out_size, void* d_ws, size_t ws_size,
                              hipStream_t stream) {
    const float* beft = (const float*)d_in[0];
    const float* Wb  = (const float*)d_in[4];
    const float* bb  = (const float*)d_in[5];
    const float* g1  = (const float*)d_in[6];
    const float* b1  = (const float*)d_in[7];
    const float* g2  = (const float*)d_in[8];
    const float* b2  = (const float*)d_in[9];
    const float* c1w = (const float*)d_in[10];
    const float* c1b = (const float*)d_in[11];
    const float* pa  = (const float*)d_in[12];
    const float* c2w = (const float*)d_in[13];
    const float* c2b = (const float*)d_in[14];
    const float* c3w = (const float*)d_in[15];
    const float* c3b = (const float*)d_in[16];
    const float* W1  = (const float*)d_in[17];
    const float* b1v = (const float*)d_in[18];
    const float* W2  = (const float*)d_in[19];
    const float* b2v = (const float*)d_in[20];
    float* out = (float*)d_out;
    char* ws = (char*)d_ws;

    // layout (overlays are temporally disjoint):
    float*          f    = (float*)(ws + 0);                   // 432,000 B [dead after attn]
    float*          cat  = (float*)(ws + 524288);              // 6,048,000 B [dead after conv]
    unsigned short* W1Tp = (unsigned short*)(ws + 8388608);    // 524,288 B (packed frag order)
    unsigned short* W2T  = (unsigned short*)(ws + 8912896);    // 4,194,304 B
    unsigned short* y1   = (unsigned short*)(ws + 13107200);   // 33,554,432 B
    unsigned short* A2   = (unsigned short*)(ws + 13107200);   // 12,582,912 B [bert phase, overlays y1]
    unsigned short* B2T  = (unsigned short*)(ws + 25690112);   // 393,216 B    [bert phase, within y1]
    float*          bpart= (float*)(ws + 46661632);            // 2,097,152 B  [bert phase]
    unsigned short* Ap   = (unsigned short*)(ws + 46661632);   // Apool chunk  [conv/gemm1 phase]
    float*          part = (float*)(ws + 46661632);            // 33,554,432 B [gemm2 phase]

    long avail = (long)ws_size - 46661632L;
    long tpc = avail / (128L * 1024L * 2L);
    if (tpc < 1) tpc = 1;
    if (tpc > 500) tpc = 500;

    split_beft<<<2048, 256, 0, stream>>>(beft, A2);
    b2t_build<<<768, 256, 0, stream>>>(Wb, B2T);
    bert_mfma<<<dim3(16, 4), 256, 0, stream>>>(A2, B2T, bpart);
    bert_reduce<<<L_RES, 64, 0, stream>>>(bpart, bb, f);
    window_attn<<<L_RES, 64, 0, stream>>>(f, g1, b1, g2, b2, cat);
    w1tp_build<<<1024, 256, 0, stream>>>(W1, W1Tp);
    transpose_to_bf16<<<dim3(256, 8), 256, 0, stream>>>(W2, W2T, 8192, 256, 8192);
    // y1 pad rows 2000..2047 NOT zeroed: gemm2 garbage from those A-rows lands only
    // in part rows >= 2000, which reduce2 never reads.

    for (long t0 = 0; t0 < 500; t0 += tpc) {
        long nt = (500 - t0 < tpc) ? (500 - t0) : tpc;
        conv_pool<<<(int)(nt * 4), 256, 0, stream>>>(cat, c1w, c1b, pa, c2w, c2b,
                                                     c3w, c3b, Ap, (int)(t0 * 4));
        gemm1k<<<(int)nt, 256, 0, stream>>>(Ap, W1Tp, b1v, y1, t0 * 128);
    }
    gemm_tile8<false, 4><<<256, 512, 0, stream>>>(
        y1, 8192, W2T, 8192, 8, nullptr, nullptr, part, 0);
    reduce2<<<L_RES, 256, 0, stream>>>(part, b2v, out);
}